// Round 1
// baseline (2988.258 us; speedup 1.0000x reference)
//
#include <hip/hip_runtime.h>

// ---- problem constants (fixed by the reference) ----
constexpr int NTOK = 2048 * 64;   // T*B tokens
constexpr int HID  = 1024;
constexpr int DIM  = 256;
constexpr int NCB  = 512;

// ---- tiling ----
constexpr int TILE_M = 32;        // tokens per workgroup
constexpr int BLOCK  = 256;       // threads (4 waves)
constexpr int KS     = 16;        // staged K-slice rows
constexpr int EST    = 260;       // padded row stride (floats) for e/q tile: 260*4B, 16B-aligned rows, banks 4m
constexpr int WST    = 260;       // padded row stride for staged weight/codebook tiles
constexpr int H1ST   = 20;        // padded row stride for h1 slice (80B rows -> 16B aligned, banks distinct)

#define FMA4(ACC, OFS, S, B)                         \
  ACC[(OFS) + 0] = fmaf((S), (B).x, ACC[(OFS) + 0]); \
  ACC[(OFS) + 1] = fmaf((S), (B).y, ACC[(OFS) + 1]); \
  ACC[(OFS) + 2] = fmaf((S), (B).z, ACC[(OFS) + 2]); \
  ACC[(OFS) + 3] = fmaf((S), (B).w, ACC[(OFS) + 3]);

// copy 16 consecutive floats global->LDS (both 16B aligned)
#define STAGE16(SRC, DST)                              \
  {                                                    \
    float4 s0_ = *(const float4*)((SRC) + 0);          \
    float4 s1_ = *(const float4*)((SRC) + 4);          \
    float4 s2_ = *(const float4*)((SRC) + 8);          \
    float4 s3_ = *(const float4*)((SRC) + 12);         \
    *(float4*)((DST) + 0)  = s0_;                      \
    *(float4*)((DST) + 4)  = s1_;                      \
    *(float4*)((DST) + 8)  = s2_;                      \
    *(float4*)((DST) + 12) = s3_;                      \
  }

__global__ __launch_bounds__(BLOCK, 2) void vqvae_fused(
    const float* __restrict__ x,    // (NTOK, 2)
    const float* __restrict__ we1,  // (2, 1024)
    const float* __restrict__ be1,  // (1024)
    const float* __restrict__ we2,  // (1024, 256)
    const float* __restrict__ be2,  // (256)
    const float* __restrict__ cb,   // (512, 256)
    const float* __restrict__ wd1,  // (256, 1024)
    const float* __restrict__ bd1,  // (1024)
    const float* __restrict__ wd2,  // (1024, 1)
    const float* __restrict__ bd2,  // (1)
    float* __restrict__ out)        // (NTOK, 1)
{
  __shared__ float ls_e[TILE_M * EST];   // 33280 B : e tile, later reused as q tile
  __shared__ float ls_w[KS * WST];       // 16640 B : staged we2 / codebook / wd1 slices
  __shared__ float ls_h1[TILE_M * H1ST]; //  2560 B : h1 K-slice
  __shared__ float ls_x[TILE_M][2];
  __shared__ float ls_nrm[16];

  const int t    = threadIdx.x;
  const int tok0 = blockIdx.x * TILE_M;
  const int tm   = t >> 4;     // 0..15
  const int tn   = t & 15;     // 0..15
  const int m0   = tm * 2;     // token-pair base for GEMM phases

  // ---- load x tile (32 tokens x 2) ----
  if (t < TILE_M * 2) ls_x[t >> 1][t & 1] = x[tok0 * 2 + t];
  __syncthreads();

  // =====================================================================
  // Phase 1+2: e[32][256] = relu(x@we1+be1) @ we2 + be2   (K=1024 in 16-slices)
  // thread (tm,tn): rows {m0,m0+1}, cols n = tn*4 + j*64 + i  (j,i in 0..3)
  // =====================================================================
  float acc0[16], acc1[16];
#pragma unroll
  for (int i = 0; i < 16; ++i) { acc0[i] = 0.f; acc1[i] = 0.f; }

#pragma unroll 1
  for (int ks = 0; ks < HID / KS; ++ks) {
    const int kb = ks * KS;
    // h1 slice (32x16): two elements per thread
    {
      int id = t, m = id >> 4, kk = id & 15, k = kb + kk;
      float v = fmaf(ls_x[m][0], we1[k], fmaf(ls_x[m][1], we1[HID + k], be1[k]));
      ls_h1[m * H1ST + kk] = fmaxf(v, 0.f);
      id = t + BLOCK; m = id >> 4; kk = id & 15; k = kb + kk;
      v = fmaf(ls_x[m][0], we1[k], fmaf(ls_x[m][1], we1[HID + k], be1[k]));
      ls_h1[m * H1ST + kk] = fmaxf(v, 0.f);
    }
    // stage we2[kb+tm, tn*16 .. +15]
    STAGE16(we2 + (kb + tm) * DIM + tn * 16, ls_w + tm * WST + tn * 16);
    __syncthreads();

#pragma unroll
    for (int kk4 = 0; kk4 < KS / 4; ++kk4) {
      const float4 a0 = *(const float4*)(ls_h1 + m0 * H1ST + kk4 * 4);
      const float4 a1 = *(const float4*)(ls_h1 + (m0 + 1) * H1ST + kk4 * 4);
      const float A0[4] = {a0.x, a0.y, a0.z, a0.w};
      const float A1[4] = {a1.x, a1.y, a1.z, a1.w};
#pragma unroll
      for (int kv = 0; kv < 4; ++kv) {
        const float av0 = A0[kv], av1 = A1[kv];
        const float4* brow = (const float4*)(ls_w + (kk4 * 4 + kv) * WST);
#pragma unroll
        for (int j = 0; j < 4; ++j) {
          const float4 b = brow[tn + j * 16];
          FMA4(acc0, j * 4, av0, b);
          FMA4(acc1, j * 4, av1, b);
        }
      }
    }
    __syncthreads();
  }

  // finalize e (+be2) and park in LDS
#pragma unroll
  for (int j = 0; j < 4; ++j) {
    const int n = tn * 4 + j * 64;
    const float4 bb = *(const float4*)(be2 + n);
    float4 e0, e1;
    e0.x = acc0[j*4+0] + bb.x; e0.y = acc0[j*4+1] + bb.y;
    e0.z = acc0[j*4+2] + bb.z; e0.w = acc0[j*4+3] + bb.w;
    e1.x = acc1[j*4+0] + bb.x; e1.y = acc1[j*4+1] + bb.y;
    e1.z = acc1[j*4+2] + bb.z; e1.w = acc1[j*4+3] + bb.w;
    *(float4*)(ls_e + m0 * EST + n)       = e0;
    *(float4*)(ls_e + (m0 + 1) * EST + n) = e1;
  }
  __syncthreads();

  // =====================================================================
  // Phase 3: argmin_k ||c_k||^2 - 2 e.c_k  (||e||^2 constant per token).
  // thread (pm = t>>3, pc = t&7): token pm, codes {pc, pc+8} per 16-code tile.
  // Strict < with ascending index order == jnp.argmin first-min semantics.
  // =====================================================================
  const int pm = t >> 3;
  const int pc = t & 7;
  float bestd  = 3.402823466e38f;
  int bestidx  = 0;

#pragma unroll 1
  for (int tile = 0; tile < NCB / 16; ++tile) {
    STAGE16(cb + (tile * 16 + tm) * DIM + tn * 16, ls_w + tm * WST + tn * 16);
    __syncthreads();
    // row norms of the staged 16 codes
    {
      const float4* row = (const float4*)(ls_w + tm * WST + tn * 16);
      const float4 r0 = row[0], r1 = row[1], r2 = row[2], r3 = row[3];
      float p = r0.x*r0.x + r0.y*r0.y + r0.z*r0.z + r0.w*r0.w
              + r1.x*r1.x + r1.y*r1.y + r1.z*r1.z + r1.w*r1.w
              + r2.x*r2.x + r2.y*r2.y + r2.z*r2.z + r2.w*r2.w
              + r3.x*r3.x + r3.y*r3.y + r3.z*r3.z + r3.w*r3.w;
      p += __shfl_xor(p, 1); p += __shfl_xor(p, 2);
      p += __shfl_xor(p, 4); p += __shfl_xor(p, 8);
      if (tn == 0) ls_nrm[tm] = p;
    }
    __syncthreads();
    {
      const float4* erow = (const float4*)(ls_e + pm * EST);
      const float4* c0r  = (const float4*)(ls_w + pc * WST);
      const float4* c1r  = (const float4*)(ls_w + (pc + 8) * WST);
      float s0 = 0.f, s1 = 0.f;
#pragma unroll 4
      for (int d4 = 0; d4 < DIM / 4; ++d4) {
        const float4 e4 = erow[d4];
        const float4 a  = c0r[d4];
        const float4 b  = c1r[d4];
        s0 = fmaf(e4.x, a.x, s0); s0 = fmaf(e4.y, a.y, s0);
        s0 = fmaf(e4.z, a.z, s0); s0 = fmaf(e4.w, a.w, s0);
        s1 = fmaf(e4.x, b.x, s1); s1 = fmaf(e4.y, b.y, s1);
        s1 = fmaf(e4.z, b.z, s1); s1 = fmaf(e4.w, b.w, s1);
      }
      const float d0 = ls_nrm[pc]     - 2.f * s0;
      const float d1 = ls_nrm[pc + 8] - 2.f * s1;
      const int i0 = tile * 16 + pc;
      if (d0 < bestd) { bestd = d0; bestidx = i0; }
      if (d1 < bestd) { bestd = d1; bestidx = i0 + 8; }
    }
    __syncthreads();
  }

  // argmin reduce over the 8 lanes of this token (tie -> smaller index)
#pragma unroll
  for (int off = 1; off < 8; off <<= 1) {
    const float od = __shfl_xor(bestd, off);
    const int   oi = __shfl_xor(bestidx, off);
    if (od < bestd || (od == bestd && oi < bestidx)) { bestd = od; bestidx = oi; }
  }
  // gather q = codebook[bestidx] into ls_e (8 lanes x 32 floats per token)
  {
    const float4* src = (const float4*)(cb + bestidx * DIM + pc * 32);
    float4* dst = (float4*)(ls_e + pm * EST + pc * 32);
#pragma unroll
    for (int i = 0; i < 8; ++i) dst[i] = src[i];
  }
  __syncthreads();

  // =====================================================================
  // Phase 4+5: out = relu(q@wd1+bd1) @ wd2 + bd2   (N=1024 in 4 chunks of 256)
  // =====================================================================
  float outp0 = 0.f, outp1 = 0.f;
#pragma unroll 1
  for (int chunk = 0; chunk < 4; ++chunk) {
    float hacc0[16], hacc1[16];
#pragma unroll
    for (int i = 0; i < 16; ++i) { hacc0[i] = 0.f; hacc1[i] = 0.f; }

#pragma unroll 1
    for (int ks = 0; ks < DIM / KS; ++ks) {
      const int kb = ks * KS;
      STAGE16(wd1 + (kb + tm) * HID + chunk * 256 + tn * 16,
              ls_w + tm * WST + tn * 16);
      __syncthreads();
#pragma unroll
      for (int kk4 = 0; kk4 < KS / 4; ++kk4) {
        const float4 a0 = *(const float4*)(ls_e + m0 * EST + kb + kk4 * 4);
        const float4 a1 = *(const float4*)(ls_e + (m0 + 1) * EST + kb + kk4 * 4);
        const float A0[4] = {a0.x, a0.y, a0.z, a0.w};
        const float A1[4] = {a1.x, a1.y, a1.z, a1.w};
#pragma unroll
        for (int kv = 0; kv < 4; ++kv) {
          const float av0 = A0[kv], av1 = A1[kv];
          const float4* brow = (const float4*)(ls_w + (kk4 * 4 + kv) * WST);
#pragma unroll
          for (int j = 0; j < 4; ++j) {
            const float4 b = brow[tn + j * 16];
            FMA4(hacc0, j * 4, av0, b);
            FMA4(hacc1, j * 4, av1, b);
          }
        }
      }
      __syncthreads();
    }
    // epilogue: relu(+bd1), dot with wd2
#pragma unroll
    for (int j = 0; j < 4; ++j) {
      const int n = chunk * 256 + tn * 4 + j * 64;
      const float4 b1 = *(const float4*)(bd1 + n);
      const float4 w2 = *(const float4*)(wd2 + n);
      float h;
      h = fmaxf(hacc0[j*4+0] + b1.x, 0.f); outp0 = fmaf(h, w2.x, outp0);
      h = fmaxf(hacc0[j*4+1] + b1.y, 0.f); outp0 = fmaf(h, w2.y, outp0);
      h = fmaxf(hacc0[j*4+2] + b1.z, 0.f); outp0 = fmaf(h, w2.z, outp0);
      h = fmaxf(hacc0[j*4+3] + b1.w, 0.f); outp0 = fmaf(h, w2.w, outp0);
      h = fmaxf(hacc1[j*4+0] + b1.x, 0.f); outp1 = fmaf(h, w2.x, outp1);
      h = fmaxf(hacc1[j*4+1] + b1.y, 0.f); outp1 = fmaf(h, w2.y, outp1);
      h = fmaxf(hacc1[j*4+2] + b1.z, 0.f); outp1 = fmaf(h, w2.z, outp1);
      h = fmaxf(hacc1[j*4+3] + b1.w, 0.f); outp1 = fmaf(h, w2.w, outp1);
    }
  }

  // reduce partial outputs over the 16 tn lanes
#pragma unroll
  for (int off = 1; off < 16; off <<= 1) {
    outp0 += __shfl_xor(outp0, off);
    outp1 += __shfl_xor(outp1, off);
  }
  if (tn == 0) {
    const float b = bd2[0];
    out[tok0 + m0]     = outp0 + b;
    out[tok0 + m0 + 1] = outp1 + b;
  }
}

extern "C" void kernel_launch(void* const* d_in, const int* in_sizes, int n_in,
                              void* d_out, int out_size, void* d_ws, size_t ws_size,
                              hipStream_t stream) {
  (void)in_sizes; (void)n_in; (void)d_ws; (void)ws_size; (void)out_size;
  const float* x   = (const float*)d_in[0];
  const float* we1 = (const float*)d_in[1];
  const float* be1 = (const float*)d_in[2];
  const float* we2 = (const float*)d_in[3];
  const float* be2 = (const float*)d_in[4];
  const float* cb  = (const float*)d_in[5];
  const float* wd1 = (const float*)d_in[6];
  const float* bd1 = (const float*)d_in[7];
  const float* wd2 = (const float*)d_in[8];
  const float* bd2 = (const float*)d_in[9];
  float* out = (float*)d_out;

  dim3 grid(NTOK / TILE_M);   // 4096 blocks, 32 tokens each
  dim3 block(BLOCK);
  hipLaunchKernelGGL(vqvae_fused, grid, block, 0, stream,
                     x, we1, be1, we2, be2, cb, wd1, bd1, wd2, bd2, out);
}

// Round 4
// 1427.657 us; speedup vs baseline: 2.0931x; 2.0931x over previous
//
#include <hip/hip_runtime.h>

typedef unsigned int u32;
typedef __attribute__((ext_vector_type(8))) _Float16 f16x8;
typedef __attribute__((ext_vector_type(4))) float    f32x4;
typedef __attribute__((ext_vector_type(4))) u32      u32x4;

constexpr int NTOK = 2048 * 64;
constexpr int HID  = 1024;
constexpr int DIM  = 256;
constexpr int NCB  = 512;

constexpr int TILE_M = 64;
constexpr int BLOCK  = 512;

// ---- workspace layout (bytes) ----
constexpr size_t OFF_WE2H = 0;            // 512 frags * 512 halfs = 512KB
constexpr size_t OFF_WE2L = 512u << 10;
constexpr size_t OFF_WD1H = 1024u << 10;  // 512 frags
constexpr size_t OFF_WD1L = 1536u << 10;
constexpr size_t OFF_CBTH = 2048u << 10;  // 256 frags = 256KB
constexpr size_t OFF_CBTL = 2304u << 10;
constexpr size_t OFF_CBHL = 2560u << 10;  // 512*256 u32 = 512KB
constexpr size_t OFF_NRM  = 3072u << 10;  // 512 f32

// LDS strides (u32 units); both ≡ 4 (mod 32) -> ds_read_b128 quarters are ≤2-way
constexpr int EST  = 260;   // e/q tile stride
constexpr int H1ST = 132;   // h1 chunk stride

__device__ inline u32 pack_hl(float v) {
  _Float16 h = (_Float16)v;
  _Float16 l = (_Float16)(v - (float)h);
  u32 uh = (u32)__builtin_bit_cast(unsigned short, h);
  u32 ul = (u32)__builtin_bit_cast(unsigned short, l);
  return uh | (ul << 16);
}

__device__ inline float hl2f(u32 p) {
  _Float16 h = __builtin_bit_cast(_Float16, (unsigned short)(p & 0xFFFFu));
  _Float16 l = __builtin_bit_cast(_Float16, (unsigned short)(p >> 16));
  return (float)h + (float)l;
}

// 8 packed u32 (hi|lo<<16) -> two f16x8 fragments
__device__ inline void unpack8(const u32* p, f16x8& hi, f16x8& lo) {
  u32x4 q0 = *(const u32x4*)p;
  u32x4 q1 = *(const u32x4*)(p + 4);
  u32x4 h, l;
  h.x = (q0.x & 0xFFFFu) | (q0.y << 16);  l.x = (q0.x >> 16) | (q0.y & 0xFFFF0000u);
  h.y = (q0.z & 0xFFFFu) | (q0.w << 16);  l.y = (q0.z >> 16) | (q0.w & 0xFFFF0000u);
  h.z = (q1.x & 0xFFFFu) | (q1.y << 16);  l.z = (q1.x >> 16) | (q1.y & 0xFFFF0000u);
  h.w = (q1.z & 0xFFFFu) | (q1.w << 16);  l.w = (q1.z >> 16) | (q1.w & 0xFFFF0000u);
  hi = __builtin_bit_cast(f16x8, h);
  lo = __builtin_bit_cast(f16x8, l);
}

__device__ inline f32x4 mfma16(f16x8 a, f16x8 b, f32x4 c) {
  return __builtin_amdgcn_mfma_f32_16x16x32_f16(a, b, c, 0, 0, 0);
}

// ======================= prep 1: fragment packing =======================
// B-frag convention (16x16x32): lane l holds B[kt*32 + (l>>4)*8 + j][nt*16 + (l&15)], j=0..7.
// dst: frag f, lane l -> halfs [(f*64+l)*8 .. +7]. we2: f=nt*32+kt (nt<16,kt<32);
// wd1: f=nt*8+kt (nt<64,kt<8); cbT (B[k][n]=cb[n][k]): f=nt*8+kt (nt<32,kt<8).
__global__ void prep_frags(const float* __restrict__ we2,
                           const float* __restrict__ wd1,
                           const float* __restrict__ cb,
                           char* __restrict__ ws) {
  int tid  = blockIdx.x * 256 + threadIdx.x;   // 1280 frags * 64 lanes
  int f    = tid >> 6;
  int lane = tid & 63;
  int lr = lane & 15, lg = lane >> 4;
  float v[8];
  _Float16 *dh, *dl;
  int fo;
  if (f < 512) {                // we2 (1024 x 256)
    int nt = f >> 5, kt = f & 31;
    int kb = kt * 32 + lg * 8, col = nt * 16 + lr;
#pragma unroll
    for (int j = 0; j < 8; ++j) v[j] = we2[(kb + j) * DIM + col];
    dh = (_Float16*)(ws + OFF_WE2H); dl = (_Float16*)(ws + OFF_WE2L); fo = f;
  } else if (f < 1024) {        // wd1 (256 x 1024)
    int fp = f - 512;
    int nt = fp >> 3, kt = fp & 7;
    int kb = kt * 32 + lg * 8, col = nt * 16 + lr;
#pragma unroll
    for (int j = 0; j < 8; ++j) v[j] = wd1[(kb + j) * HID + col];
    dh = (_Float16*)(ws + OFF_WD1H); dl = (_Float16*)(ws + OFF_WD1L); fo = fp;
  } else {                      // cbT: B[k][n] = cb[n][k]  (256 x 512)
    int fp = f - 1024;
    int nt = fp >> 3, kt = fp & 7;
    const float* src = cb + (nt * 16 + lr) * DIM + kt * 32 + lg * 8;
#pragma unroll
    for (int j = 0; j < 8; ++j) v[j] = src[j];
    dh = (_Float16*)(ws + OFF_CBTH); dl = (_Float16*)(ws + OFF_CBTL); fo = fp;
  }
  f16x8 hv, lv;
#pragma unroll
  for (int j = 0; j < 8; ++j) {
    _Float16 h = (_Float16)v[j];
    hv[j] = h;
    lv[j] = (_Float16)(v[j] - (float)h);
  }
  ((f16x8*)dh)[fo * 64 + lane] = hv;
  ((f16x8*)dl)[fo * 64 + lane] = lv;
}

// ======================= prep 2: cb hl-rows + norms =======================
__global__ void prep_cb(const float* __restrict__ cb, char* __restrict__ ws) {
  int b = blockIdx.x;          // codebook row
  int l = threadIdx.x;         // 64 threads
  u32*   cbhl = (u32*)(ws + OFF_CBHL);
  float* nrm  = (float*)(ws + OFF_NRM);
  float4 v = ((const float4*)(cb + b * DIM))[l];
  float s = (v.x * v.x + v.y * v.y) + (v.z * v.z + v.w * v.w);
#pragma unroll
  for (int off = 1; off < 64; off <<= 1) s += __shfl_xor(s, off);
  if (l == 0) nrm[b] = s;
  u32x4 pk;
  pk.x = pack_hl(v.x); pk.y = pack_hl(v.y); pk.z = pack_hl(v.z); pk.w = pack_hl(v.w);
  *(u32x4*)&cbhl[b * DIM + l * 4] = pk;
}

// ======================= main fused kernel =======================
__global__ __launch_bounds__(BLOCK, 2) void vq_main(
    const float* __restrict__ x,
    const float* __restrict__ we1, const float* __restrict__ be1,
    const float* __restrict__ be2,
    const float* __restrict__ cb,
    const float* __restrict__ bd1, const float* __restrict__ wd2,
    const float* __restrict__ bd2,
    const char* __restrict__ ws,
    float* __restrict__ out) {
  __shared__ u32   ls_e[TILE_M * EST];    // 66560 B : e (hl-packed), later q
  __shared__ u32   ls_h1[TILE_M * H1ST]; // 33792 B : h1 chunk; later cand lists
  __shared__ float ls_nrm[NCB];          //  2048 B
  __shared__ float ls_x[TILE_M][2];
  __shared__ int   ls_idx[TILE_M];
  __shared__ float ls_outp[TILE_M][8];

  const f16x8* we2hf = (const f16x8*)(ws + OFF_WE2H);
  const f16x8* we2lf = (const f16x8*)(ws + OFF_WE2L);
  const f16x8* wd1hf = (const f16x8*)(ws + OFF_WD1H);
  const f16x8* wd1lf = (const f16x8*)(ws + OFF_WD1L);
  const f16x8* cbthf = (const f16x8*)(ws + OFF_CBTH);
  const f16x8* cbtlf = (const f16x8*)(ws + OFF_CBTL);
  const u32*   cbhl  = (const u32*)  (ws + OFF_CBHL);
  const float* nrmg  = (const float*)(ws + OFF_NRM);

  const int t    = threadIdx.x;
  const int w    = t >> 6;       // wave 0..7
  const int lane = t & 63;
  const int lr   = lane & 15;    // MFMA col / A-row selector
  const int lg   = lane >> 4;    // MFMA k-group / row-group
  const int tok0 = blockIdx.x * TILE_M;

  ls_nrm[t] = nrmg[t];                       // 512 == BLOCK
  if (t < TILE_M * 2) ls_x[t >> 1][t & 1] = x[tok0 * 2 + t];
  __syncthreads();

  // ================= phase 1+2: e = relu(x@we1+be1) @ we2 + be2 =================
  // wave w owns N-tiles {w, w+8}; all 4 M-tiles. K chunked by 128 (h1 staged in LDS).
  f32x4 eacc[2][4];
#pragma unroll
  for (int g = 0; g < 2; ++g)
#pragma unroll
    for (int mt = 0; mt < 4; ++mt) eacc[g][mt] = (f32x4){0.f, 0.f, 0.f, 0.f};

#pragma unroll 1
  for (int ch = 0; ch < 8; ++ch) {
    {  // h1 slice rows=64, cols=ch*128..+127 ; thread -> row t>>3, 16 cols
      const int m = t >> 3, c0 = (t & 7) * 16;
      const float x0 = ls_x[m][0], x1 = ls_x[m][1];
      const float4* w0 = (const float4*)(we1 + ch * 128 + c0);
      const float4* w1 = (const float4*)(we1 + HID + ch * 128 + c0);
      const float4* bb = (const float4*)(be1 + ch * 128 + c0);
#pragma unroll
      for (int q = 0; q < 4; ++q) {
        float4 a = w0[q], b = w1[q], c = bb[q];
        u32x4 pk;
        pk.x = pack_hl(fmaxf(fmaf(x0, a.x, fmaf(x1, b.x, c.x)), 0.f));
        pk.y = pack_hl(fmaxf(fmaf(x0, a.y, fmaf(x1, b.y, c.y)), 0.f));
        pk.z = pack_hl(fmaxf(fmaf(x0, a.z, fmaf(x1, b.z, c.z)), 0.f));
        pk.w = pack_hl(fmaxf(fmaf(x0, a.w, fmaf(x1, b.w, c.w)), 0.f));
        *(u32x4*)&ls_h1[m * H1ST + c0 + q * 4] = pk;
      }
    }
    __syncthreads();
#pragma unroll
    for (int kt = 0; kt < 4; ++kt) {
      f16x8 ahi[4], alo[4];
#pragma unroll
      for (int mt = 0; mt < 4; ++mt)
        unpack8(&ls_h1[(mt * 16 + lr) * H1ST + kt * 32 + lg * 8], ahi[mt], alo[mt]);
#pragma unroll
      for (int g = 0; g < 2; ++g) {
        const int nt = w + g * 8;
        const int fidx = (nt * 32 + ch * 4 + kt) * 64 + lane;
        f16x8 bh = we2hf[fidx];
        f16x8 bl = we2lf[fidx];
#pragma unroll
        for (int mt = 0; mt < 4; ++mt) {
          eacc[g][mt] = mfma16(ahi[mt], bh, eacc[g][mt]);
          eacc[g][mt] = mfma16(alo[mt], bh, eacc[g][mt]);
          eacc[g][mt] = mfma16(ahi[mt], bl, eacc[g][mt]);
        }
      }
    }
    __syncthreads();
  }
  // epilogue: +be2, hl-pack into ls_e
#pragma unroll
  for (int g = 0; g < 2; ++g) {
    const int col = (w + g * 8) * 16 + lr;
    const float b2v = be2[col];
#pragma unroll
    for (int mt = 0; mt < 4; ++mt)
#pragma unroll
      for (int r = 0; r < 4; ++r) {
        const int row = mt * 16 + lg * 4 + r;
        ls_e[row * EST + col] = pack_hl(eacc[g][mt][r] + b2v);
      }
  }
  __syncthreads();

  // ================= phase 3: screened argmin over 512 codes =================
  // wave w owns codes [w*64, w*64+64): nt = w*4+ntl. Per lane: 16 token-streams (mt,r).
  float bd_[16];
  int   bi_[16];
#pragma unroll
  for (int s = 0; s < 16; ++s) { bd_[s] = 3.402823466e38f; bi_[s] = 0; }

#pragma unroll 1
  for (int ntl = 0; ntl < 4; ++ntl) {
    const int nt = w * 4 + ntl;
    f32x4 acc[4];
#pragma unroll
    for (int mt = 0; mt < 4; ++mt) acc[mt] = (f32x4){0.f, 0.f, 0.f, 0.f};
#pragma unroll
    for (int kt = 0; kt < 8; ++kt) {
      f16x8 ahi[4], alo[4];
#pragma unroll
      for (int mt = 0; mt < 4; ++mt)
        unpack8(&ls_e[(mt * 16 + lr) * EST + kt * 32 + lg * 8], ahi[mt], alo[mt]);
      const int fidx = (nt * 8 + kt) * 64 + lane;
      f16x8 bh = cbthf[fidx];
      f16x8 bl = cbtlf[fidx];
#pragma unroll
      for (int mt = 0; mt < 4; ++mt) {
        acc[mt] = mfma16(ahi[mt], bh, acc[mt]);
        acc[mt] = mfma16(alo[mt], bh, acc[mt]);
        acc[mt] = mfma16(ahi[mt], bl, acc[mt]);
      }
    }
    const int code = nt * 16 + lr;
    const float nr = ls_nrm[code];
#pragma unroll
    for (int mt = 0; mt < 4; ++mt)
#pragma unroll
      for (int r = 0; r < 4; ++r) {
        const float d = fmaf(-2.f, acc[mt][r], nr);
        const int s = mt * 4 + r;
        const bool lt = d < bd_[s];       // strict < : first index wins ties
        bd_[s] = lt ? d : bd_[s];
        bi_[s] = lt ? code : bi_[s];
      }
  }
  // reduce across the 16-lane code dim (lr), lexicographic (d, idx)
#pragma unroll
  for (int off = 1; off < 16; off <<= 1) {
#pragma unroll
    for (int s = 0; s < 16; ++s) {
      const float od = __shfl_xor(bd_[s], off);
      const int   oi = __shfl_xor(bi_[s], off);
      const bool better = (od < bd_[s]) || (od == bd_[s] && oi < bi_[s]);
      bd_[s] = better ? od : bd_[s];
      bi_[s] = better ? oi : bi_[s];
    }
  }
  // per-wave winners -> LDS (alias ls_h1: floats [0..512), ints [512..1024))
  float* cand_d = (float*)ls_h1;
  int*   cand_i = (int*)(ls_h1 + TILE_M * 8);
  if (lr == 0) {
#pragma unroll
    for (int s = 0; s < 16; ++s) {
      const int token = (s >> 2) * 16 + lg * 4 + (s & 3);
      cand_d[token * 8 + w] = bd_[s];
      cand_i[token * 8 + w] = bi_[s];
    }
  }
  __syncthreads();

  // fp32 recompute of the 8 wave-winners; exact lexicographic pick (jnp first-min)
  {
    const int token = t >> 3, c = t & 7;
    int ci = cand_i[token * 8 + c];
    const float4* crow = (const float4*)(cb + ci * DIM);
    float s = 0.f;
#pragma unroll 4
    for (int k4 = 0; k4 < 64; ++k4) {
      u32x4 p = *(const u32x4*)&ls_e[token * EST + k4 * 4];
      const float4 cv = crow[k4];
      s = fmaf(hl2f(p.x), cv.x, s);
      s = fmaf(hl2f(p.y), cv.y, s);
      s = fmaf(hl2f(p.z), cv.z, s);
      s = fmaf(hl2f(p.w), cv.w, s);
    }
    float d = fmaf(-2.f, s, ls_nrm[ci]);
#pragma unroll
    for (int off = 1; off < 8; off <<= 1) {
      const float od = __shfl_xor(d, off);
      const int   oi = __shfl_xor(ci, off);
      const bool better = (od < d) || (od == d && oi < ci);
      d = better ? od : d;
      ci = better ? oi : ci;
    }
    if (c == 0) ls_idx[token] = ci;
  }
  __syncthreads();

  // gather q (hl-packed rows) into ls_e; strided-u32 to stay ≤2-way on banks
  {
    const int token = t >> 3, part = t & 7;
    const u32* src = cbhl + ls_idx[token] * DIM;
#pragma unroll
    for (int j = 0; j < 32; ++j)
      ls_e[token * EST + part + 8 * j] = src[part + 8 * j];
  }
  __syncthreads();

  // ================= phase 4+5: out = relu(q@wd1+bd1) @ wd2 + bd2 =================
  // wave w owns N-tiles [w*8, w*8+8); h2 consumed immediately into the wd2 dot.
  float op[16];
#pragma unroll
  for (int s = 0; s < 16; ++s) op[s] = 0.f;

#pragma unroll 1
  for (int ntl = 0; ntl < 8; ++ntl) {
    const int nt = w * 8 + ntl;
    f32x4 acc[4];
#pragma unroll
    for (int mt = 0; mt < 4; ++mt) acc[mt] = (f32x4){0.f, 0.f, 0.f, 0.f};
#pragma unroll
    for (int kt = 0; kt < 8; ++kt) {
      f16x8 ahi[4], alo[4];
#pragma unroll
      for (int mt = 0; mt < 4; ++mt)
        unpack8(&ls_e[(mt * 16 + lr) * EST + kt * 32 + lg * 8], ahi[mt], alo[mt]);
      const int fidx = (nt * 8 + kt) * 64 + lane;
      f16x8 bh = wd1hf[fidx];
      f16x8 bl = wd1lf[fidx];
#pragma unroll
      for (int mt = 0; mt < 4; ++mt) {
        acc[mt] = mfma16(ahi[mt], bh, acc[mt]);
        acc[mt] = mfma16(alo[mt], bh, acc[mt]);
        acc[mt] = mfma16(ahi[mt], bl, acc[mt]);
      }
    }
    const int col = nt * 16 + lr;
    const float b1v = bd1[col], w2v = wd2[col];
#pragma unroll
    for (int mt = 0; mt < 4; ++mt)
#pragma unroll
      for (int r = 0; r < 4; ++r) {
        const float h = fmaxf(acc[mt][r] + b1v, 0.f);
        op[mt * 4 + r] = fmaf(h, w2v, op[mt * 4 + r]);
      }
  }
  // reduce over the 16 hidden-col lanes
#pragma unroll
  for (int off = 1; off < 16; off <<= 1)
#pragma unroll
    for (int s = 0; s < 16; ++s) op[s] += __shfl_xor(op[s], off);
  if (lr == 0) {
#pragma unroll
    for (int s = 0; s < 16; ++s)
      ls_outp[(s >> 2) * 16 + lg * 4 + (s & 3)][w] = op[s];
  }
  __syncthreads();
  if (t < TILE_M) {
    float v = bd2[0];
#pragma unroll
    for (int c = 0; c < 8; ++c) v += ls_outp[t][c];
    out[tok0 + t] = v;
  }
}

extern "C" void kernel_launch(void* const* d_in, const int* in_sizes, int n_in,
                              void* d_out, int out_size, void* d_ws, size_t ws_size,
                              hipStream_t stream) {
  (void)in_sizes; (void)n_in; (void)out_size; (void)ws_size;
  const float* x   = (const float*)d_in[0];
  const float* we1 = (const float*)d_in[1];
  const float* be1 = (const float*)d_in[2];
  const float* we2 = (const float*)d_in[3];
  const float* be2 = (const float*)d_in[4];
  const float* cb  = (const float*)d_in[5];
  const float* wd1 = (const float*)d_in[6];
  const float* bd1 = (const float*)d_in[7];
  const float* wd2 = (const float*)d_in[8];
  const float* bd2 = (const float*)d_in[9];
  float* out = (float*)d_out;
  char* ws = (char*)d_ws;

  // prep: fragment-pack we2/wd1/cbT (hi,lo), hl-pack cb rows, tree row-norms
  hipLaunchKernelGGL(prep_frags, dim3(320), dim3(256), 0, stream, we2, wd1, cb, ws);
  hipLaunchKernelGGL(prep_cb, dim3(NCB), dim3(64), 0, stream, cb, ws);
  // main fused VQ-VAE forward
  hipLaunchKernelGGL(vq_main, dim3(NTOK / TILE_M), dim3(BLOCK), 0, stream,
                     x, we1, be1, be2, cb, bd1, wd2, bd2, ws, out);
}

// Round 5
// 1275.509 us; speedup vs baseline: 2.3428x; 1.1193x over previous
//
#include <hip/hip_runtime.h>

typedef unsigned int u32;
typedef __attribute__((ext_vector_type(8))) _Float16 f16x8;
typedef __attribute__((ext_vector_type(4))) _Float16 f16x4;
typedef __attribute__((ext_vector_type(4))) float    f32x4;
typedef __attribute__((ext_vector_type(4))) u32      u32x4;

constexpr int NTOK = 2048 * 64;
constexpr int HID  = 1024;
constexpr int DIM  = 256;
constexpr int NCB  = 512;

constexpr int TILE_M = 64;
constexpr int BLOCK  = 512;

// ---- workspace layout (bytes) ----
constexpr size_t OFF_WE2H = 0;            // 512 frags * 1KB
constexpr size_t OFF_WE2L = 512u << 10;
constexpr size_t OFF_WD1H = 1024u << 10;  // 512 frags
constexpr size_t OFF_WD1L = 1536u << 10;
constexpr size_t OFF_CBTH = 2048u << 10;  // 256 frags
constexpr size_t OFF_CBTL = 2304u << 10;
constexpr size_t OFF_CBH  = 2560u << 10;  // cb hi plane: 512*256 f16 = 256KB
constexpr size_t OFF_CBL  = 2816u << 10;  // cb lo plane
constexpr size_t OFF_NRM  = 3072u << 10;  // 512 f32

// LDS strides in f16 units. Byte strides 528 / 272 -> dword stride ≡ 4 (mod 32):
// 16-row fragment reads touch each bank pair exactly twice (2-way = free, m136).
constexpr int ESTH = 264;   // e/q plane row stride (256 + 8 pad)
constexpr int H1SH = 136;   // h1 plane row stride (128 + 8 pad)

__device__ inline f32x4 mfma16(f16x8 a, f16x8 b, f32x4 c) {
  return __builtin_amdgcn_mfma_f32_16x16x32_f16(a, b, c, 0, 0, 0);
}

// ======================= prep 1: fragment packing (unchanged, HW-validated) =======================
// B-frag convention (16x16x32): lane l holds B[kt*32 + (l>>4)*8 + j][nt*16 + (l&15)], j=0..7.
__global__ void prep_frags(const float* __restrict__ we2,
                           const float* __restrict__ wd1,
                           const float* __restrict__ cb,
                           char* __restrict__ ws) {
  int tid  = blockIdx.x * 256 + threadIdx.x;   // 1280 frags * 64 lanes
  int f    = tid >> 6;
  int lane = tid & 63;
  int lr = lane & 15, lg = lane >> 4;
  float v[8];
  _Float16 *dh, *dl;
  int fo;
  if (f < 512) {                // we2 (1024 x 256): f = nt*32 + kt
    int nt = f >> 5, kt = f & 31;
    int kb = kt * 32 + lg * 8, col = nt * 16 + lr;
#pragma unroll
    for (int j = 0; j < 8; ++j) v[j] = we2[(kb + j) * DIM + col];
    dh = (_Float16*)(ws + OFF_WE2H); dl = (_Float16*)(ws + OFF_WE2L); fo = f;
  } else if (f < 1024) {        // wd1 (256 x 1024): f = nt*8 + kt
    int fp = f - 512;
    int nt = fp >> 3, kt = fp & 7;
    int kb = kt * 32 + lg * 8, col = nt * 16 + lr;
#pragma unroll
    for (int j = 0; j < 8; ++j) v[j] = wd1[(kb + j) * HID + col];
    dh = (_Float16*)(ws + OFF_WD1H); dl = (_Float16*)(ws + OFF_WD1L); fo = fp;
  } else {                      // cbT: B[k][n] = cb[n][k]; f = nt*8 + kt
    int fp = f - 1024;
    int nt = fp >> 3, kt = fp & 7;
    const float* src = cb + (nt * 16 + lr) * DIM + kt * 32 + lg * 8;
#pragma unroll
    for (int j = 0; j < 8; ++j) v[j] = src[j];
    dh = (_Float16*)(ws + OFF_CBTH); dl = (_Float16*)(ws + OFF_CBTL); fo = fp;
  }
  f16x8 hv, lv;
#pragma unroll
  for (int j = 0; j < 8; ++j) {
    _Float16 h = (_Float16)v[j];
    hv[j] = h;
    lv[j] = (_Float16)(v[j] - (float)h);
  }
  ((f16x8*)dh)[fo * 64 + lane] = hv;
  ((f16x8*)dl)[fo * 64 + lane] = lv;
}

// ======================= prep 2: cb hi/lo planes + norms =======================
__global__ void prep_cb(const float* __restrict__ cb, char* __restrict__ ws) {
  int b = blockIdx.x;          // codebook row
  int l = threadIdx.x;         // 64 threads
  _Float16* cbh = (_Float16*)(ws + OFF_CBH);
  _Float16* cbl = (_Float16*)(ws + OFF_CBL);
  float*    nrm = (float*)(ws + OFF_NRM);
  float4 v = ((const float4*)(cb + b * DIM))[l];
  float s = (v.x * v.x + v.y * v.y) + (v.z * v.z + v.w * v.w);
#pragma unroll
  for (int off = 1; off < 64; off <<= 1) s += __shfl_xor(s, off);
  if (l == 0) nrm[b] = s;
  f16x4 hv, lv;
  float vv[4] = {v.x, v.y, v.z, v.w};
#pragma unroll
  for (int j = 0; j < 4; ++j) {
    _Float16 h = (_Float16)vv[j];
    hv[j] = h;
    lv[j] = (_Float16)(vv[j] - (float)h);
  }
  *(f16x4*)(cbh + b * DIM + l * 4) = hv;
  *(f16x4*)(cbl + b * DIM + l * 4) = lv;
}

// ======================= main fused kernel =======================
__global__ __launch_bounds__(BLOCK, 2) void vq_main(
    const float* __restrict__ x,
    const float* __restrict__ we1, const float* __restrict__ be1,
    const float* __restrict__ be2,
    const float* __restrict__ cb,
    const float* __restrict__ bd1, const float* __restrict__ wd2,
    const float* __restrict__ bd2,
    const char* __restrict__ ws,
    float* __restrict__ out) {
  // 67584 B buffer: during phase 1+2 the front 34816 B holds the h1 hi/lo chunk
  // planes; afterwards the whole buffer holds the e (later q) hi/lo planes.
  __shared__ __align__(16) _Float16 ls_buf[33792];
  __shared__ float ls_nrm[NCB];          // 2048 B
  __shared__ float ls_x[TILE_M][2];
  __shared__ int   ls_idx[TILE_M];
  __shared__ float ls_outp[TILE_M][8];
  __shared__ float cand_d[TILE_M * 8];
  __shared__ int   cand_i[TILE_M * 8];

  _Float16* eh  = ls_buf;                 // e hi plane [64][264]
  _Float16* el  = ls_buf + 16896;         // e lo plane
  _Float16* h1h = ls_buf;                 // h1 hi chunk plane [64][136]
  _Float16* h1l = ls_buf + 8704;          // h1 lo chunk plane

  const f16x8* we2hf = (const f16x8*)(ws + OFF_WE2H);
  const f16x8* we2lf = (const f16x8*)(ws + OFF_WE2L);
  const f16x8* wd1hf = (const f16x8*)(ws + OFF_WD1H);
  const f16x8* wd1lf = (const f16x8*)(ws + OFF_WD1L);
  const f16x8* cbthf = (const f16x8*)(ws + OFF_CBTH);
  const f16x8* cbtlf = (const f16x8*)(ws + OFF_CBTL);
  const _Float16* cbh = (const _Float16*)(ws + OFF_CBH);
  const _Float16* cbl = (const _Float16*)(ws + OFF_CBL);
  const float* nrmg  = (const float*)(ws + OFF_NRM);

  const int t    = threadIdx.x;
  const int w    = t >> 6;       // wave 0..7
  const int lane = t & 63;
  const int lr   = lane & 15;    // MFMA col / A-row selector
  const int lg   = lane >> 4;    // MFMA k-group / row-group
  const int tok0 = blockIdx.x * TILE_M;

  ls_nrm[t] = nrmg[t];                       // 512 == BLOCK
  if (t < TILE_M * 2) ls_x[t >> 1][t & 1] = x[tok0 * 2 + t];
  __syncthreads();

  // ================= phase 1+2: e = relu(x@we1+be1) @ we2 + be2 =================
  // Per ch (K-chunk of 128): cooperatively stage h1 hi/lo planes, then MFMA.
  // Wave w owns N-tiles {w, w+8}.
  f32x4 eacc[2][4];
#pragma unroll
  for (int g = 0; g < 2; ++g)
#pragma unroll
    for (int mt = 0; mt < 4; ++mt) eacc[g][mt] = (f32x4){0.f, 0.f, 0.f, 0.f};

  const int sm = t >> 3, sc0 = (t & 7) * 16;  // staging: row sm, 16 cols
  const float sx0 = ls_x[sm][0], sx1 = ls_x[sm][1];

#pragma unroll 1
  for (int ch = 0; ch < 8; ++ch) {
    {  // h1 chunk: rows 64 x cols 128, split hi/lo f16 planes
      const float4* w0 = (const float4*)(we1 + ch * 128 + sc0);
      const float4* w1 = (const float4*)(we1 + HID + ch * 128 + sc0);
      const float4* bb = (const float4*)(be1 + ch * 128 + sc0);
      f16x8 hv[2], lv[2];
#pragma unroll
      for (int q = 0; q < 4; ++q) {
        float4 a = w0[q], b = w1[q], c = bb[q];
        float vv[4];
        vv[0] = fmaxf(fmaf(sx0, a.x, fmaf(sx1, b.x, c.x)), 0.f);
        vv[1] = fmaxf(fmaf(sx0, a.y, fmaf(sx1, b.y, c.y)), 0.f);
        vv[2] = fmaxf(fmaf(sx0, a.z, fmaf(sx1, b.z, c.z)), 0.f);
        vv[3] = fmaxf(fmaf(sx0, a.w, fmaf(sx1, b.w, c.w)), 0.f);
#pragma unroll
        for (int j = 0; j < 4; ++j) {
          _Float16 h = (_Float16)vv[j];
          hv[q >> 1][(q & 1) * 4 + j] = h;
          lv[q >> 1][(q & 1) * 4 + j] = (_Float16)(vv[j] - (float)h);
        }
      }
      *(f16x8*)(h1h + sm * H1SH + sc0)     = hv[0];
      *(f16x8*)(h1h + sm * H1SH + sc0 + 8) = hv[1];
      *(f16x8*)(h1l + sm * H1SH + sc0)     = lv[0];
      *(f16x8*)(h1l + sm * H1SH + sc0 + 8) = lv[1];
    }
    __syncthreads();
#pragma unroll
    for (int kt = 0; kt < 4; ++kt) {
      f16x8 ah[4], al[4];
#pragma unroll
      for (int mt = 0; mt < 4; ++mt) {
        ah[mt] = *(const f16x8*)(h1h + (mt * 16 + lr) * H1SH + kt * 32 + lg * 8);
        al[mt] = *(const f16x8*)(h1l + (mt * 16 + lr) * H1SH + kt * 32 + lg * 8);
      }
#pragma unroll
      for (int g = 0; g < 2; ++g) {
        const int fidx = ((w + g * 8) * 32 + ch * 4 + kt) * 64 + lane;
        f16x8 bh = we2hf[fidx];
        f16x8 bl = we2lf[fidx];
#pragma unroll
        for (int mt = 0; mt < 4; ++mt) {
          eacc[g][mt] = mfma16(ah[mt], bh, eacc[g][mt]);
          eacc[g][mt] = mfma16(al[mt], bh, eacc[g][mt]);
          eacc[g][mt] = mfma16(ah[mt], bl, eacc[g][mt]);
        }
      }
    }
    __syncthreads();   // all h1 reads done before next chunk (or e epilogue) overwrites
  }

  // epilogue: +be2, split hi/lo into e planes (overwrites h1 region; barrier above covers)
#pragma unroll
  for (int g = 0; g < 2; ++g) {
    const int col = (w + g * 8) * 16 + lr;
    const float b2v = be2[col];
#pragma unroll
    for (int mt = 0; mt < 4; ++mt)
#pragma unroll
      for (int r = 0; r < 4; ++r) {
        const int row = mt * 16 + lg * 4 + r;
        const float v = eacc[g][mt][r] + b2v;
        const _Float16 h = (_Float16)v;
        eh[row * ESTH + col] = h;
        el[row * ESTH + col] = (_Float16)(v - (float)h);
      }
  }
  __syncthreads();

  // ================= phase 3: screened argmin over 512 codes =================
  // wave w owns codes [w*64, w*64+64): nt = w*4 + ntc*2 + n2.
  float bd_[16];
  int   bi_[16];
#pragma unroll
  for (int s = 0; s < 16; ++s) { bd_[s] = 3.402823466e38f; bi_[s] = 0; }

#pragma unroll 1
  for (int ntc = 0; ntc < 2; ++ntc) {
    f32x4 acc[2][4];
#pragma unroll
    for (int n2 = 0; n2 < 2; ++n2)
#pragma unroll
      for (int mt = 0; mt < 4; ++mt) acc[n2][mt] = (f32x4){0.f, 0.f, 0.f, 0.f};
#pragma unroll
    for (int kt = 0; kt < 8; ++kt) {
      f16x8 ah[4], al[4];
#pragma unroll
      for (int mt = 0; mt < 4; ++mt) {
        ah[mt] = *(const f16x8*)(eh + (mt * 16 + lr) * ESTH + kt * 32 + lg * 8);
        al[mt] = *(const f16x8*)(el + (mt * 16 + lr) * ESTH + kt * 32 + lg * 8);
      }
#pragma unroll
      for (int n2 = 0; n2 < 2; ++n2) {
        const int nt = w * 4 + ntc * 2 + n2;
        const int fidx = (nt * 8 + kt) * 64 + lane;
        f16x8 bh = cbthf[fidx];
        f16x8 bl = cbtlf[fidx];
#pragma unroll
        for (int mt = 0; mt < 4; ++mt) {
          acc[n2][mt] = mfma16(ah[mt], bh, acc[n2][mt]);
          acc[n2][mt] = mfma16(al[mt], bh, acc[n2][mt]);
          acc[n2][mt] = mfma16(ah[mt], bl, acc[n2][mt]);
        }
      }
    }
#pragma unroll
    for (int n2 = 0; n2 < 2; ++n2) {
      const int code = (w * 4 + ntc * 2 + n2) * 16 + lr;
      const float nr = ls_nrm[code];
#pragma unroll
      for (int mt = 0; mt < 4; ++mt)
#pragma unroll
        for (int r = 0; r < 4; ++r) {
          const float d = fmaf(-2.f, acc[n2][mt][r], nr);
          const int s = mt * 4 + r;
          const bool lt = d < bd_[s];       // strict < : first index wins ties
          bd_[s] = lt ? d : bd_[s];
          bi_[s] = lt ? code : bi_[s];
        }
    }
  }
  // reduce across the 16-lane code dim (lr), lexicographic (d, idx)
#pragma unroll
  for (int off = 1; off < 16; off <<= 1) {
#pragma unroll
    for (int s = 0; s < 16; ++s) {
      const float od = __shfl_xor(bd_[s], off);
      const int   oi = __shfl_xor(bi_[s], off);
      const bool better = (od < bd_[s]) || (od == bd_[s] && oi < bi_[s]);
      bd_[s] = better ? od : bd_[s];
      bi_[s] = better ? oi : bi_[s];
    }
  }
  if (lr == 0) {
#pragma unroll
    for (int s = 0; s < 16; ++s) {
      const int token = (s >> 2) * 16 + lg * 4 + (s & 3);
      cand_d[token * 8 + w] = bd_[s];
      cand_i[token * 8 + w] = bi_[s];
    }
  }
  __syncthreads();

  // fp32 recompute of the 8 wave-winners (exact e = hi+lo); jnp first-min pick
  {
    const int token = t >> 3, c = t & 7;
    int ci = cand_i[token * 8 + c];
    const float4* crow = (const float4*)(cb + ci * DIM);
    float s = 0.f;
#pragma unroll 4
    for (int k8 = 0; k8 < 32; ++k8) {
      f16x8 hv = *(const f16x8*)(eh + token * ESTH + k8 * 8);
      f16x8 lv = *(const f16x8*)(el + token * ESTH + k8 * 8);
      const float4 c0 = crow[k8 * 2];
      const float4 c1 = crow[k8 * 2 + 1];
      s = fmaf((float)hv[0] + (float)lv[0], c0.x, s);
      s = fmaf((float)hv[1] + (float)lv[1], c0.y, s);
      s = fmaf((float)hv[2] + (float)lv[2], c0.z, s);
      s = fmaf((float)hv[3] + (float)lv[3], c0.w, s);
      s = fmaf((float)hv[4] + (float)lv[4], c1.x, s);
      s = fmaf((float)hv[5] + (float)lv[5], c1.y, s);
      s = fmaf((float)hv[6] + (float)lv[6], c1.z, s);
      s = fmaf((float)hv[7] + (float)lv[7], c1.w, s);
    }
    float d = fmaf(-2.f, s, ls_nrm[ci]);
#pragma unroll
    for (int off = 1; off < 8; off <<= 1) {
      const float od = __shfl_xor(d, off);
      const int   oi = __shfl_xor(ci, off);
      const bool better = (od < d) || (od == d && oi < ci);
      d = better ? od : d;
      ci = better ? oi : ci;
    }
    if (c == 0) ls_idx[token] = ci;
  }
  __syncthreads();

  // gather q rows (pre-split planes) into e planes
  {
    const int token = t >> 3, part = t & 7;
    const u32x4* srch = (const u32x4*)(cbh + ls_idx[token] * DIM + part * 32);
    const u32x4* srcl = (const u32x4*)(cbl + ls_idx[token] * DIM + part * 32);
    u32x4* dsth = (u32x4*)(eh + token * ESTH + part * 32);
    u32x4* dstl = (u32x4*)(el + token * ESTH + part * 32);
#pragma unroll
    for (int i = 0; i < 4; ++i) { dsth[i] = srch[i]; dstl[i] = srcl[i]; }
  }
  __syncthreads();

  // ================= phase 4+5: out = relu(q@wd1+bd1) @ wd2 + bd2 =================
  // wave w owns N-tiles [w*8, w*8+8) in pairs.
  float op[16];
#pragma unroll
  for (int s = 0; s < 16; ++s) op[s] = 0.f;

#pragma unroll 1
  for (int ntc = 0; ntc < 4; ++ntc) {
    f32x4 acc[2][4];
#pragma unroll
    for (int n2 = 0; n2 < 2; ++n2)
#pragma unroll
      for (int mt = 0; mt < 4; ++mt) acc[n2][mt] = (f32x4){0.f, 0.f, 0.f, 0.f};
#pragma unroll
    for (int kt = 0; kt < 8; ++kt) {
      f16x8 ah[4], al[4];
#pragma unroll
      for (int mt = 0; mt < 4; ++mt) {
        ah[mt] = *(const f16x8*)(eh + (mt * 16 + lr) * ESTH + kt * 32 + lg * 8);
        al[mt] = *(const f16x8*)(el + (mt * 16 + lr) * ESTH + kt * 32 + lg * 8);
      }
#pragma unroll
      for (int n2 = 0; n2 < 2; ++n2) {
        const int nt = w * 8 + ntc * 2 + n2;
        const int fidx = (nt * 8 + kt) * 64 + lane;
        f16x8 bh = wd1hf[fidx];
        f16x8 bl = wd1lf[fidx];
#pragma unroll
        for (int mt = 0; mt < 4; ++mt) {
          acc[n2][mt] = mfma16(ah[mt], bh, acc[n2][mt]);
          acc[n2][mt] = mfma16(al[mt], bh, acc[n2][mt]);
          acc[n2][mt] = mfma16(ah[mt], bl, acc[n2][mt]);
        }
      }
    }
#pragma unroll
    for (int n2 = 0; n2 < 2; ++n2) {
      const int col = (w * 8 + ntc * 2 + n2) * 16 + lr;
      const float b1v = bd1[col], w2v = wd2[col];
#pragma unroll
      for (int mt = 0; mt < 4; ++mt)
#pragma unroll
        for (int r = 0; r < 4; ++r) {
          const float h = fmaxf(acc[n2][mt][r] + b1v, 0.f);
          op[mt * 4 + r] = fmaf(h, w2v, op[mt * 4 + r]);
        }
    }
  }
  // reduce over the 16 hidden-col lanes
#pragma unroll
  for (int off = 1; off < 16; off <<= 1)
#pragma unroll
    for (int s = 0; s < 16; ++s) op[s] += __shfl_xor(op[s], off);
  if (lr == 0) {
#pragma unroll
    for (int s = 0; s < 16; ++s)
      ls_outp[(s >> 2) * 16 + lg * 4 + (s & 3)][w] = op[s];
  }
  __syncthreads();
  if (t < TILE_M) {
    float v = bd2[0];
#pragma unroll
    for (int c = 0; c < 8; ++c) v += ls_outp[t][c];
    out[tok0 + t] = v;
  }
}

extern "C" void kernel_launch(void* const* d_in, const int* in_sizes, int n_in,
                              void* d_out, int out_size, void* d_ws, size_t ws_size,
                              hipStream_t stream) {
  (void)in_sizes; (void)n_in; (void)out_size; (void)ws_size;
  const float* x   = (const float*)d_in[0];
  const float* we1 = (const float*)d_in[1];
  const float* be1 = (const float*)d_in[2];
  const float* we2 = (const float*)d_in[3];
  const float* be2 = (const float*)d_in[4];
  const float* cb  = (const float*)d_in[5];
  const float* wd1 = (const float*)d_in[6];
  const float* bd1 = (const float*)d_in[7];
  const float* wd2 = (const float*)d_in[8];
  const float* bd2 = (const float*)d_in[9];
  float* out = (float*)d_out;
  char* ws = (char*)d_ws;

  hipLaunchKernelGGL(prep_frags, dim3(320), dim3(256), 0, stream, we2, wd1, cb, ws);
  hipLaunchKernelGGL(prep_cb, dim3(NCB), dim3(64), 0, stream, cb, ws);
  hipLaunchKernelGGL(vq_main, dim3(NTOK / TILE_M), dim3(BLOCK), 0, stream,
                     x, we1, be1, be2, cb, bd1, wd2, bd2, ws, out);
}

// Round 9
// 1226.326 us; speedup vs baseline: 2.4368x; 1.0401x over previous
//
#include <hip/hip_runtime.h>

typedef unsigned int u32;
typedef __attribute__((ext_vector_type(8))) _Float16 f16x8;
typedef __attribute__((ext_vector_type(4))) _Float16 f16x4;
typedef __attribute__((ext_vector_type(4))) float    f32x4;
typedef __attribute__((ext_vector_type(4))) u32      u32x4;

constexpr int NTOK = 2048 * 64;
constexpr int HID  = 1024;
constexpr int DIM  = 256;
constexpr int NCB  = 512;

constexpr int TILE_M = 64;
constexpr int BLOCK  = 512;

// ---- workspace layout (bytes) ----
constexpr size_t OFF_WE2H = 0;            // 512 frags * 1KB
constexpr size_t OFF_WE2L = 512u << 10;
constexpr size_t OFF_WD1H = 1024u << 10;  // 512 frags
constexpr size_t OFF_WD1L = 1536u << 10;
constexpr size_t OFF_CBTH = 2048u << 10;  // 256 frags
constexpr size_t OFF_CBTL = 2304u << 10;
constexpr size_t OFF_CBH  = 2560u << 10;  // cb hi plane: 512*256 f16 = 256KB
constexpr size_t OFF_CBL  = 2816u << 10;  // cb lo plane
constexpr size_t OFF_NRM  = 3072u << 10;  // 512 f32

// LDS strides in f16 units. Byte strides 528 / 272 -> dword stride ≡ 4 (mod 32):
// a 16-row b128 fragment read touches every bank exactly twice (2-way = free).
constexpr int ESTH = 264;   // e/q plane row stride (256 + 8 pad)
constexpr int H1SH = 136;   // h1 plane row stride (128 + 8 pad)

__device__ inline f32x4 mfma16(f16x8 a, f16x8 b, f32x4 c) {
  return __builtin_amdgcn_mfma_f32_16x16x32_f16(a, b, c, 0, 0, 0);
}

// ======================= prep 1: fragment packing (HW-validated, unchanged) =======================
// B-frag convention (16x16x32): lane l holds B[kt*32 + (l>>4)*8 + j][nt*16 + (l&15)], j=0..7.
__global__ void prep_frags(const float* __restrict__ we2,
                           const float* __restrict__ wd1,
                           const float* __restrict__ cb,
                           char* __restrict__ ws) {
  int tid  = blockIdx.x * 256 + threadIdx.x;   // 1280 frags * 64 lanes
  int f    = tid >> 6;
  int lane = tid & 63;
  int lr = lane & 15, lg = lane >> 4;
  float v[8];
  _Float16 *dh, *dl;
  int fo;
  if (f < 512) {                // we2 (1024 x 256): f = nt*32 + kt
    int nt = f >> 5, kt = f & 31;
    int kb = kt * 32 + lg * 8, col = nt * 16 + lr;
#pragma unroll
    for (int j = 0; j < 8; ++j) v[j] = we2[(kb + j) * DIM + col];
    dh = (_Float16*)(ws + OFF_WE2H); dl = (_Float16*)(ws + OFF_WE2L); fo = f;
  } else if (f < 1024) {        // wd1 (256 x 1024): f = nt*8 + kt
    int fp = f - 512;
    int nt = fp >> 3, kt = fp & 7;
    int kb = kt * 32 + lg * 8, col = nt * 16 + lr;
#pragma unroll
    for (int j = 0; j < 8; ++j) v[j] = wd1[(kb + j) * HID + col];
    dh = (_Float16*)(ws + OFF_WD1H); dl = (_Float16*)(ws + OFF_WD1L); fo = fp;
  } else {                      // cbT: B[k][n] = cb[n][k]; f = nt*8 + kt
    int fp = f - 1024;
    int nt = fp >> 3, kt = fp & 7;
    const float* src = cb + (nt * 16 + lr) * DIM + kt * 32 + lg * 8;
#pragma unroll
    for (int j = 0; j < 8; ++j) v[j] = src[j];
    dh = (_Float16*)(ws + OFF_CBTH); dl = (_Float16*)(ws + OFF_CBTL); fo = fp;
  }
  f16x8 hv, lv;
#pragma unroll
  for (int j = 0; j < 8; ++j) {
    _Float16 h = (_Float16)v[j];
    hv[j] = h;
    lv[j] = (_Float16)(v[j] - (float)h);
  }
  ((f16x8*)dh)[fo * 64 + lane] = hv;
  ((f16x8*)dl)[fo * 64 + lane] = lv;
}

// ======================= prep 2: cb hi/lo planes + norms =======================
__global__ void prep_cb(const float* __restrict__ cb, char* __restrict__ ws) {
  int b = blockIdx.x;          // codebook row
  int l = threadIdx.x;         // 64 threads
  _Float16* cbh = (_Float16*)(ws + OFF_CBH);
  _Float16* cbl = (_Float16*)(ws + OFF_CBL);
  float*    nrm = (float*)(ws + OFF_NRM);
  float4 v = ((const float4*)(cb + b * DIM))[l];
  float s = (v.x * v.x + v.y * v.y) + (v.z * v.z + v.w * v.w);
#pragma unroll
  for (int off = 1; off < 64; off <<= 1) s += __shfl_xor(s, off);
  if (l == 0) nrm[b] = s;
  f16x4 hv, lv;
  float vv[4] = {v.x, v.y, v.z, v.w};
#pragma unroll
  for (int j = 0; j < 4; ++j) {
    _Float16 h = (_Float16)vv[j];
    hv[j] = h;
    lv[j] = (_Float16)(vv[j] - (float)h);
  }
  *(f16x4*)(cbh + b * DIM + l * 4) = hv;
  *(f16x4*)(cbl + b * DIM + l * 4) = lv;
}

// ======================= main fused kernel =======================
// __launch_bounds__(512, 4): 4 waves/EU -> unified reg cap 128/wave -> 2 blocks/CU.
__global__ __launch_bounds__(BLOCK, 4) void vq_main(
    const float* __restrict__ x,
    const float* __restrict__ we1, const float* __restrict__ be1,
    const float* __restrict__ be2,
    const float* __restrict__ cb,
    const float* __restrict__ bd1, const float* __restrict__ wd2,
    const float* __restrict__ bd2,
    const char* __restrict__ ws,
    float* __restrict__ out) {
  // 67584 B buffer: during phase 1+2 the front 34816 B holds the h1 hi/lo chunk
  // planes; afterwards the whole buffer holds the e (later q) hi/lo planes.
  __shared__ __align__(16) _Float16 ls_buf[33792];
  __shared__ float ls_nrm[NCB];          // 2048 B
  __shared__ float ls_x[TILE_M][2];
  __shared__ int   ls_idx[TILE_M];
  __shared__ float ls_outp[TILE_M][4];
  __shared__ float cand_d[TILE_M * 4];
  __shared__ int   cand_i[TILE_M * 4];

  _Float16* eh  = ls_buf;                 // e hi plane [64][264]
  _Float16* el  = ls_buf + 16896;         // e lo plane
  _Float16* h1h = ls_buf;                 // h1 hi chunk plane [64][136]
  _Float16* h1l = ls_buf + 8704;          // h1 lo chunk plane

  const f16x8* we2hf = (const f16x8*)(ws + OFF_WE2H);
  const f16x8* we2lf = (const f16x8*)(ws + OFF_WE2L);
  const f16x8* wd1hf = (const f16x8*)(ws + OFF_WD1H);
  const f16x8* wd1lf = (const f16x8*)(ws + OFF_WD1L);
  const f16x8* cbthf = (const f16x8*)(ws + OFF_CBTH);
  const f16x8* cbtlf = (const f16x8*)(ws + OFF_CBTL);
  const _Float16* cbh = (const _Float16*)(ws + OFF_CBH);
  const _Float16* cbl = (const _Float16*)(ws + OFF_CBL);
  const float* nrmg  = (const float*)(ws + OFF_NRM);

  const int t    = threadIdx.x;
  const int w    = t >> 6;       // wave 0..7
  const int lane = t & 63;
  const int lr   = lane & 15;    // MFMA col / A-row selector
  const int lg   = lane >> 4;    // MFMA k-group / row-group
  const int tok0 = blockIdx.x * TILE_M;
  const int th   = w & 1;        // token half (phases 3,4+5): mt in {2*th, 2*th+1}

  ls_nrm[t] = nrmg[t];                       // 512 == BLOCK
  if (t < TILE_M * 2) ls_x[t >> 1][t & 1] = x[tok0 * 2 + t];
  __syncthreads();

  // ================= phase 1+2: e = relu(x@we1+be1) @ we2 + be2 =================
  // Wave w owns N-tiles {w, w+8}. Per ch (K-chunk 128): stage h1 planes, MFMA.
  // mt loop split in halves: A-frag live = 16 regs (not 32).
  f32x4 eacc[2][4];
#pragma unroll
  for (int g = 0; g < 2; ++g)
#pragma unroll
    for (int mt = 0; mt < 4; ++mt) eacc[g][mt] = (f32x4){0.f, 0.f, 0.f, 0.f};

  const int sm = t >> 3, sc0 = (t & 7) * 16;  // staging: row sm, 16 cols
  const float sx0 = ls_x[sm][0], sx1 = ls_x[sm][1];

#pragma unroll 1
  for (int ch = 0; ch < 8; ++ch) {
    {  // h1 chunk: rows 64 x cols 128, split hi/lo f16 planes
      const float4* w0 = (const float4*)(we1 + ch * 128 + sc0);
      const float4* w1 = (const float4*)(we1 + HID + ch * 128 + sc0);
      const float4* bb = (const float4*)(be1 + ch * 128 + sc0);
      f16x8 hv[2], lv[2];
#pragma unroll
      for (int q = 0; q < 4; ++q) {
        float4 a = w0[q], b = w1[q], c = bb[q];
        float vv[4];
        vv[0] = fmaxf(fmaf(sx0, a.x, fmaf(sx1, b.x, c.x)), 0.f);
        vv[1] = fmaxf(fmaf(sx0, a.y, fmaf(sx1, b.y, c.y)), 0.f);
        vv[2] = fmaxf(fmaf(sx0, a.z, fmaf(sx1, b.z, c.z)), 0.f);
        vv[3] = fmaxf(fmaf(sx0, a.w, fmaf(sx1, b.w, c.w)), 0.f);
#pragma unroll
        for (int j = 0; j < 4; ++j) {
          _Float16 h = (_Float16)vv[j];
          hv[q >> 1][(q & 1) * 4 + j] = h;
          lv[q >> 1][(q & 1) * 4 + j] = (_Float16)(vv[j] - (float)h);
        }
      }
      *(f16x8*)(h1h + sm * H1SH + sc0)     = hv[0];
      *(f16x8*)(h1h + sm * H1SH + sc0 + 8) = hv[1];
      *(f16x8*)(h1l + sm * H1SH + sc0)     = lv[0];
      *(f16x8*)(h1l + sm * H1SH + sc0 + 8) = lv[1];
    }
    __syncthreads();
#pragma unroll
    for (int kt = 0; kt < 4; ++kt) {
#pragma unroll
      for (int mth = 0; mth < 2; ++mth) {
        f16x8 ah[2], al[2];
#pragma unroll
        for (int m2 = 0; m2 < 2; ++m2) {
          const int mt = mth * 2 + m2;
          ah[m2] = *(const f16x8*)(h1h + (mt * 16 + lr) * H1SH + kt * 32 + lg * 8);
          al[m2] = *(const f16x8*)(h1l + (mt * 16 + lr) * H1SH + kt * 32 + lg * 8);
        }
#pragma unroll
        for (int g = 0; g < 2; ++g) {
          const int fidx = ((w + g * 8) * 32 + ch * 4 + kt) * 64 + lane;
          f16x8 bh = we2hf[fidx];
          f16x8 bl = we2lf[fidx];
#pragma unroll
          for (int m2 = 0; m2 < 2; ++m2) {
            eacc[g][mth * 2 + m2] = mfma16(ah[m2], bh, eacc[g][mth * 2 + m2]);
            eacc[g][mth * 2 + m2] = mfma16(al[m2], bh, eacc[g][mth * 2 + m2]);
            eacc[g][mth * 2 + m2] = mfma16(ah[m2], bl, eacc[g][mth * 2 + m2]);
          }
        }
      }
    }
    __syncthreads();   // all h1 reads done before next chunk (or e epilogue) overwrites
  }

  // epilogue: +be2, split hi/lo into e planes (overwrites h1 region; barrier above covers)
#pragma unroll
  for (int g = 0; g < 2; ++g) {
    const int col = (w + g * 8) * 16 + lr;
    const float b2v = be2[col];
#pragma unroll
    for (int mt = 0; mt < 4; ++mt)
#pragma unroll
      for (int r = 0; r < 4; ++r) {
        const int row = mt * 16 + lg * 4 + r;
        const float v = eacc[g][mt][r] + b2v;
        const _Float16 h = (_Float16)v;
        eh[row * ESTH + col] = h;
        el[row * ESTH + col] = (_Float16)(v - (float)h);
      }
  }
  __syncthreads();

  // ================= phase 3: screened argmin over 512 codes =================
  // wave w: code range cr = w>>1 (128 codes), token half th (2 M-tiles, 32 tokens).
  // 8 streams/lane, acc[2] -> minimal live registers.
  {
    const int cr = w >> 1;
    float bd_[8];
    int   bi_[8];
#pragma unroll
    for (int s = 0; s < 8; ++s) { bd_[s] = 3.402823466e38f; bi_[s] = 0; }

#pragma unroll 1
    for (int ntl = 0; ntl < 8; ++ntl) {
      const int nt = cr * 8 + ntl;
      f32x4 acc[2];
#pragma unroll
      for (int m2 = 0; m2 < 2; ++m2) acc[m2] = (f32x4){0.f, 0.f, 0.f, 0.f};
#pragma unroll
      for (int kt = 0; kt < 8; ++kt) {
        f16x8 ah[2], al[2];
#pragma unroll
        for (int m2 = 0; m2 < 2; ++m2) {
          const int mt = th * 2 + m2;
          ah[m2] = *(const f16x8*)(eh + (mt * 16 + lr) * ESTH + kt * 32 + lg * 8);
          al[m2] = *(const f16x8*)(el + (mt * 16 + lr) * ESTH + kt * 32 + lg * 8);
        }
        const int fidx = (nt * 8 + kt) * 64 + lane;
        f16x8 bh = cbthf[fidx];
        f16x8 bl = cbtlf[fidx];
#pragma unroll
        for (int m2 = 0; m2 < 2; ++m2) {
          acc[m2] = mfma16(ah[m2], bh, acc[m2]);
          acc[m2] = mfma16(al[m2], bh, acc[m2]);
          acc[m2] = mfma16(ah[m2], bl, acc[m2]);
        }
      }
      const int code = nt * 16 + lr;
      const float nr = ls_nrm[code];
#pragma unroll
      for (int m2 = 0; m2 < 2; ++m2)
#pragma unroll
        for (int r = 0; r < 4; ++r) {
          const float d = fmaf(-2.f, acc[m2][r], nr);
          const int s = m2 * 4 + r;
          const bool lt = d < bd_[s];       // strict < : first index wins ties
          bd_[s] = lt ? d : bd_[s];
          bi_[s] = lt ? code : bi_[s];
        }
    }
    // reduce across the 16-lane code dim (lr), lexicographic (d, idx)
#pragma unroll
    for (int off = 1; off < 16; off <<= 1) {
#pragma unroll
      for (int s = 0; s < 8; ++s) {
        const float od = __shfl_xor(bd_[s], off);
        const int   oi = __shfl_xor(bi_[s], off);
        const bool better = (od < bd_[s]) || (od == bd_[s] && oi < bi_[s]);
        bd_[s] = better ? od : bd_[s];
        bi_[s] = better ? oi : bi_[s];
      }
    }
    if (lr == 0) {
#pragma unroll
      for (int s = 0; s < 8; ++s) {
        const int token = (th * 2 + (s >> 2)) * 16 + lg * 4 + (s & 3);
        cand_d[token * 4 + cr] = bd_[s];
        cand_i[token * 4 + cr] = bi_[s];
      }
    }
  }
  __syncthreads();

  // fp32 recompute of the 4 range-winners (exact e = hi+lo); jnp first-min pick
  if (t < TILE_M * 4) {
    const int token = t >> 2, c = t & 3;
    int ci = cand_i[token * 4 + c];
    const float4* crow = (const float4*)(cb + ci * DIM);
    float s = 0.f;
#pragma unroll 4
    for (int k8 = 0; k8 < 32; ++k8) {
      f16x8 hv = *(const f16x8*)(eh + token * ESTH + k8 * 8);
      f16x8 lv = *(const f16x8*)(el + token * ESTH + k8 * 8);
      const float4 c0 = crow[k8 * 2];
      const float4 c1 = crow[k8 * 2 + 1];
      s = fmaf((float)hv[0] + (float)lv[0], c0.x, s);
      s = fmaf((float)hv[1] + (float)lv[1], c0.y, s);
      s = fmaf((float)hv[2] + (float)lv[2], c0.z, s);
      s = fmaf((float)hv[3] + (float)lv[3], c0.w, s);
      s = fmaf((float)hv[4] + (float)lv[4], c1.x, s);
      s = fmaf((float)hv[5] + (float)lv[5], c1.y, s);
      s = fmaf((float)hv[6] + (float)lv[6], c1.z, s);
      s = fmaf((float)hv[7] + (float)lv[7], c1.w, s);
    }
    float d = fmaf(-2.f, s, ls_nrm[ci]);
#pragma unroll
    for (int off = 1; off < 4; off <<= 1) {
      const float od = __shfl_xor(d, off);
      const int   oi = __shfl_xor(ci, off);
      const bool better = (od < d) || (od == d && oi < ci);
      d = better ? od : d;
      ci = better ? oi : ci;
    }
    if (c == 0) ls_idx[token] = ci;
  }
  __syncthreads();

  // gather q rows (pre-split planes) into e planes
  {
    const int token = t >> 3, part = t & 7;
    const u32x4* srch = (const u32x4*)(cbh + ls_idx[token] * DIM + part * 32);
    const u32x4* srcl = (const u32x4*)(cbl + ls_idx[token] * DIM + part * 32);
    u32x4* dsth = (u32x4*)(eh + token * ESTH + part * 32);
    u32x4* dstl = (u32x4*)(el + token * ESTH + part * 32);
#pragma unroll
    for (int i = 0; i < 4; ++i) { dsth[i] = srch[i]; dstl[i] = srcl[i]; }
  }
  __syncthreads();

  // ================= phase 4+5: out = relu(q@wd1+bd1) @ wd2 + bd2 =================
  // wave w: N-range nr_ = w>>1 (16 N-tiles of wd1), token half th (2 M-tiles).
  {
    const int nr_ = w >> 1;
    float op[8];
#pragma unroll
    for (int s = 0; s < 8; ++s) op[s] = 0.f;

#pragma unroll 1
    for (int ntl = 0; ntl < 16; ++ntl) {
      const int nt = nr_ * 16 + ntl;
      f32x4 acc[2];
#pragma unroll
      for (int m2 = 0; m2 < 2; ++m2) acc[m2] = (f32x4){0.f, 0.f, 0.f, 0.f};
#pragma unroll
      for (int kt = 0; kt < 8; ++kt) {
        f16x8 ah[2], al[2];
#pragma unroll
        for (int m2 = 0; m2 < 2; ++m2) {
          const int mt = th * 2 + m2;
          ah[m2] = *(const f16x8*)(eh + (mt * 16 + lr) * ESTH + kt * 32 + lg * 8);
          al[m2] = *(const f16x8*)(el + (mt * 16 + lr) * ESTH + kt * 32 + lg * 8);
        }
        const int fidx = (nt * 8 + kt) * 64 + lane;
        f16x8 bh = wd1hf[fidx];
        f16x8 bl = wd1lf[fidx];
#pragma unroll
        for (int m2 = 0; m2 < 2; ++m2) {
          acc[m2] = mfma16(ah[m2], bh, acc[m2]);
          acc[m2] = mfma16(al[m2], bh, acc[m2]);
          acc[m2] = mfma16(ah[m2], bl, acc[m2]);
        }
      }
      const int col = nt * 16 + lr;
      const float b1v = bd1[col], w2v = wd2[col];
#pragma unroll
      for (int m2 = 0; m2 < 2; ++m2)
#pragma unroll
        for (int r = 0; r < 4; ++r) {
          const float h = fmaxf(acc[m2][r] + b1v, 0.f);
          op[m2 * 4 + r] = fmaf(h, w2v, op[m2 * 4 + r]);
        }
    }
    // reduce over the 16 hidden-col lanes
#pragma unroll
    for (int off = 1; off < 16; off <<= 1)
#pragma unroll
      for (int s = 0; s < 8; ++s) op[s] += __shfl_xor(op[s], off);
    if (lr == 0) {
#pragma unroll
      for (int s = 0; s < 8; ++s) {
        const int token = (th * 2 + (s >> 2)) * 16 + lg * 4 + (s & 3);
        ls_outp[token][nr_] = op[s];
      }
    }
  }
  __syncthreads();
  if (t < TILE_M) {
    float v = bd2[0];
#pragma unroll
    for (int c = 0; c < 4; ++c) v += ls_outp[t][c];
    out[tok0 + t] = v;
  }
}

extern "C" void kernel_launch(void* const* d_in, const int* in_sizes, int n_in,
                              void* d_out, int out_size, void* d_ws, size_t ws_size,
                              hipStream_t stream) {
  (void)in_sizes; (void)n_in; (void)out_size; (void)ws_size;
  const float* x   = (const float*)d_in[0];
  const float* we1 = (const float*)d_in[1];
  const float* be1 = (const float*)d_in[2];
  const float* we2 = (const float*)d_in[3];
  const float* be2 = (const float*)d_in[4];
  const float* cb  = (const float*)d_in[5];
  const float* wd1 = (const float*)d_in[6];
  const float* bd1 = (const float*)d_in[7];
  const float* wd2 = (const float*)d_in[8];
  const float* bd2 = (const float*)d_in[9];
  float* out = (float*)d_out;
  char* ws = (char*)d_ws;

  hipLaunchKernelGGL(prep_frags, dim3(320), dim3(256), 0, stream, we2, wd1, cb, ws);
  hipLaunchKernelGGL(prep_cb, dim3(NCB), dim3(64), 0, stream, cb, ws);
  hipLaunchKernelGGL(vq_main, dim3(NTOK / TILE_M), dim3(BLOCK), 0, stream,
                     x, we1, be1, be2, cb, bd1, wd2, bd2, ws, out);
}

// Round 10
// 748.411 us; speedup vs baseline: 3.9928x; 1.6386x over previous
//
#include <hip/hip_runtime.h>

typedef unsigned int u32;
typedef __attribute__((ext_vector_type(8))) _Float16 f16x8;
typedef __attribute__((ext_vector_type(4))) _Float16 f16x4;
typedef __attribute__((ext_vector_type(4))) float    f32x4;
typedef __attribute__((ext_vector_type(4))) u32      u32x4;

constexpr int NTOK = 2048 * 64;
constexpr int HID  = 1024;
constexpr int DIM  = 256;
constexpr int NCB  = 512;

constexpr int TILE_M = 64;
constexpr int BLOCK  = 512;

// ---- workspace layout (bytes) ----
constexpr size_t OFF_WE2H = 0;            // 512 frags * 1KB
constexpr size_t OFF_WE2L = 512u << 10;
constexpr size_t OFF_WD1H = 1024u << 10;  // 512 frags
constexpr size_t OFF_WD1L = 1536u << 10;
constexpr size_t OFF_CBTH = 2048u << 10;  // 256 frags
constexpr size_t OFF_CBTL = 2304u << 10;
constexpr size_t OFF_CBH  = 2560u << 10;  // cb hi plane: 512*256 f16 = 256KB
constexpr size_t OFF_CBL  = 2816u << 10;  // cb lo plane
constexpr size_t OFF_NRM  = 3072u << 10;  // 512 f32
constexpr size_t OFF_WEPK = 3080u << 10;  // wepack: 1024 float4 = 16KB

// LDS strides in f16 units. Byte strides 528 / 272 -> dword stride ≡ 4 (mod 32):
// a 16-row b128 fragment read touches every bank exactly twice (2-way = free).
constexpr int ESTH = 264;   // e/q plane row stride (256 + 8 pad)
constexpr int H1SH = 136;   // h1 plane row stride (128 + 8 pad)

__device__ inline f32x4 mfma16(f16x8 a, f16x8 b, f32x4 c) {
  return __builtin_amdgcn_mfma_f32_16x16x32_f16(a, b, c, 0, 0, 0);
}

// ======================= prep 1: fragment packing (HW-validated, unchanged) =======================
// B-frag convention (16x16x32): lane l holds B[kt*32 + (l>>4)*8 + j][nt*16 + (l&15)], j=0..7.
__global__ void prep_frags(const float* __restrict__ we2,
                           const float* __restrict__ wd1,
                           const float* __restrict__ cb,
                           char* __restrict__ ws) {
  int tid  = blockIdx.x * 256 + threadIdx.x;   // 1280 frags * 64 lanes
  int f    = tid >> 6;
  int lane = tid & 63;
  int lr = lane & 15, lg = lane >> 4;
  float v[8];
  _Float16 *dh, *dl;
  int fo;
  if (f < 512) {                // we2 (1024 x 256): f = nt*32 + kt
    int nt = f >> 5, kt = f & 31;
    int kb = kt * 32 + lg * 8, col = nt * 16 + lr;
#pragma unroll
    for (int j = 0; j < 8; ++j) v[j] = we2[(kb + j) * DIM + col];
    dh = (_Float16*)(ws + OFF_WE2H); dl = (_Float16*)(ws + OFF_WE2L); fo = f;
  } else if (f < 1024) {        // wd1 (256 x 1024): f = nt*8 + kt
    int fp = f - 512;
    int nt = fp >> 3, kt = fp & 7;
    int kb = kt * 32 + lg * 8, col = nt * 16 + lr;
#pragma unroll
    for (int j = 0; j < 8; ++j) v[j] = wd1[(kb + j) * HID + col];
    dh = (_Float16*)(ws + OFF_WD1H); dl = (_Float16*)(ws + OFF_WD1L); fo = fp;
  } else {                      // cbT: B[k][n] = cb[n][k]; f = nt*8 + kt
    int fp = f - 1024;
    int nt = fp >> 3, kt = fp & 7;
    const float* src = cb + (nt * 16 + lr) * DIM + kt * 32 + lg * 8;
#pragma unroll
    for (int j = 0; j < 8; ++j) v[j] = src[j];
    dh = (_Float16*)(ws + OFF_CBTH); dl = (_Float16*)(ws + OFF_CBTL); fo = fp;
  }
  f16x8 hv, lv;
#pragma unroll
  for (int j = 0; j < 8; ++j) {
    _Float16 h = (_Float16)v[j];
    hv[j] = h;
    lv[j] = (_Float16)(v[j] - (float)h);
  }
  ((f16x8*)dh)[fo * 64 + lane] = hv;
  ((f16x8*)dl)[fo * 64 + lane] = lv;
}

// ======================= prep 2: cb hi/lo planes + norms =======================
__global__ void prep_cb(const float* __restrict__ cb, char* __restrict__ ws) {
  int b = blockIdx.x;          // codebook row
  int l = threadIdx.x;         // 64 threads
  _Float16* cbh = (_Float16*)(ws + OFF_CBH);
  _Float16* cbl = (_Float16*)(ws + OFF_CBL);
  float*    nrm = (float*)(ws + OFF_NRM);
  float4 v = ((const float4*)(cb + b * DIM))[l];
  float s = (v.x * v.x + v.y * v.y) + (v.z * v.z + v.w * v.w);
#pragma unroll
  for (int off = 1; off < 64; off <<= 1) s += __shfl_xor(s, off);
  if (l == 0) nrm[b] = s;
  f16x4 hv, lv;
  float vv[4] = {v.x, v.y, v.z, v.w};
#pragma unroll
  for (int j = 0; j < 4; ++j) {
    _Float16 h = (_Float16)vv[j];
    hv[j] = h;
    lv[j] = (_Float16)(vv[j] - (float)h);
  }
  *(f16x4*)(cbh + b * DIM + l * 4) = hv;
  *(f16x4*)(cbl + b * DIM + l * 4) = lv;
}

// ======================= prep 3: encoder-L1 packed table =======================
// wepack[k] = (we1[0][k], we1[1][k], be1[k], 0) -> single load stream in staging.
__global__ void prep_we(const float* __restrict__ we1,
                        const float* __restrict__ be1,
                        char* __restrict__ ws) {
  int k = blockIdx.x * 256 + threadIdx.x;   // 1024
  float4* wp = (float4*)(ws + OFF_WEPK);
  float4 o; o.x = we1[k]; o.y = we1[HID + k]; o.z = be1[k]; o.w = 0.f;
  wp[k] = o;
}

// ======================= main fused kernel =======================
// __launch_bounds__(512, 4): 4 waves/EU -> unified reg cap 128/wave -> 2 blocks/CU.
// Every phase budgeted <= ~90 arch + 32 acc regs (spill-free by construction):
//  - staging: single wepack stream, unroll-1, immediate LDS store (<=20 transient)
//  - MFMA loops: A-frag reloaded per (kt,mt) from LDS (8 live), B dist-1 dbuf
//  - phases 3/4+5: EXCLUSIVE nt per wave (no wave-pair B-frag sharing)
__global__ __launch_bounds__(BLOCK, 4) void vq_main(
    const float* __restrict__ x,
    const float* __restrict__ be2,
    const float* __restrict__ cb,
    const float* __restrict__ bd1, const float* __restrict__ wd2,
    const float* __restrict__ bd2,
    const char* __restrict__ ws,
    float* __restrict__ out) {
  // 67584 B buffer: during phase 1+2 the front 34816 B holds the h1 hi/lo chunk
  // planes; afterwards the whole buffer holds the e (later q) hi/lo planes.
  __shared__ __align__(16) _Float16 ls_buf[33792];
  __shared__ float ls_nrm[NCB];          // 2048 B
  __shared__ float ls_x[TILE_M][2];
  __shared__ int   ls_idx[TILE_M];
  __shared__ float ls_outp[TILE_M][8];
  __shared__ float cand_d[TILE_M * 8];
  __shared__ int   cand_i[TILE_M * 8];

  _Float16* eh  = ls_buf;                 // e hi plane [64][264]
  _Float16* el  = ls_buf + 16896;         // e lo plane
  _Float16* h1h = ls_buf;                 // h1 hi chunk plane [64][136]
  _Float16* h1l = ls_buf + 8704;          // h1 lo chunk plane

  const f16x8* we2hf = (const f16x8*)(ws + OFF_WE2H);
  const f16x8* we2lf = (const f16x8*)(ws + OFF_WE2L);
  const f16x8* wd1hf = (const f16x8*)(ws + OFF_WD1H);
  const f16x8* wd1lf = (const f16x8*)(ws + OFF_WD1L);
  const f16x8* cbthf = (const f16x8*)(ws + OFF_CBTH);
  const f16x8* cbtlf = (const f16x8*)(ws + OFF_CBTL);
  const _Float16* cbh = (const _Float16*)(ws + OFF_CBH);
  const _Float16* cbl = (const _Float16*)(ws + OFF_CBL);
  const float* nrmg  = (const float*)(ws + OFF_NRM);
  const float4* wpk  = (const float4*)(ws + OFF_WEPK);

  const int t    = threadIdx.x;
  const int w    = t >> 6;       // wave 0..7
  const int lane = t & 63;
  const int lr   = lane & 15;    // MFMA col / A-row selector
  const int lg   = lane >> 4;    // MFMA k-group / row-group
  const int tok0 = blockIdx.x * TILE_M;

  ls_nrm[t] = nrmg[t];                       // 512 == BLOCK
  if (t < TILE_M * 2) ls_x[t >> 1][t & 1] = x[tok0 * 2 + t];
  __syncthreads();

  // ================= phase 1+2: e = relu(x@we1+be1) @ we2 + be2 =================
  // Wave w owns N-tiles {w, w+8} (exclusive). Per ch (K-chunk 128): stage h1, MFMA.
  f32x4 eacc[2][4];
#pragma unroll
  for (int g = 0; g < 2; ++g)
#pragma unroll
    for (int mt = 0; mt < 4; ++mt) eacc[g][mt] = (f32x4){0.f, 0.f, 0.f, 0.f};

  const int sm = t >> 3, sc0 = (t & 7) * 16;  // staging: row sm, 16 cols
  const float sx0 = ls_x[sm][0], sx1 = ls_x[sm][1];

#pragma unroll 1
  for (int ch = 0; ch < 8; ++ch) {
    {  // h1 chunk staging: single packed stream, minimal transient registers
      const float4* wp = wpk + ch * 128 + sc0;
#pragma unroll 1
      for (int q = 0; q < 4; ++q) {
        float4 p0 = wp[q * 4 + 0], p1 = wp[q * 4 + 1];
        float4 p2 = wp[q * 4 + 2], p3 = wp[q * 4 + 3];
        float v0 = fmaxf(fmaf(sx0, p0.x, fmaf(sx1, p0.y, p0.z)), 0.f);
        float v1 = fmaxf(fmaf(sx0, p1.x, fmaf(sx1, p1.y, p1.z)), 0.f);
        float v2 = fmaxf(fmaf(sx0, p2.x, fmaf(sx1, p2.y, p2.z)), 0.f);
        float v3 = fmaxf(fmaf(sx0, p3.x, fmaf(sx1, p3.y, p3.z)), 0.f);
        f16x4 hv, lv;
        hv[0] = (_Float16)v0; lv[0] = (_Float16)(v0 - (float)hv[0]);
        hv[1] = (_Float16)v1; lv[1] = (_Float16)(v1 - (float)hv[1]);
        hv[2] = (_Float16)v2; lv[2] = (_Float16)(v2 - (float)hv[2]);
        hv[3] = (_Float16)v3; lv[3] = (_Float16)(v3 - (float)hv[3]);
        *(f16x4*)(h1h + sm * H1SH + sc0 + q * 4) = hv;
        *(f16x4*)(h1l + sm * H1SH + sc0 + q * 4) = lv;
      }
    }
    __syncthreads();
    {  // MFMA: B dist-1 double-buffer over kt; A reloaded per (kt,mt) from LDS
      const int fb0 = (w * 32 + ch * 4) * 64 + lane;        // nt = w
      const int fb1 = ((w + 8) * 32 + ch * 4) * 64 + lane;  // nt = w+8
      f16x8 bh0 = we2hf[fb0], bl0 = we2lf[fb0];
      f16x8 bh1 = we2hf[fb1], bl1 = we2lf[fb1];
#pragma unroll 1
      for (int kt = 0; kt < 4; ++kt) {
        const int ktn = (kt + 1 < 4) ? kt + 1 : kt;
        f16x8 nbh0 = we2hf[fb0 + ktn * 64], nbl0 = we2lf[fb0 + ktn * 64];
        f16x8 nbh1 = we2hf[fb1 + ktn * 64], nbl1 = we2lf[fb1 + ktn * 64];
#pragma unroll
        for (int mt = 0; mt < 4; ++mt) {
          f16x8 ah = *(const f16x8*)(h1h + (mt * 16 + lr) * H1SH + kt * 32 + lg * 8);
          f16x8 al = *(const f16x8*)(h1l + (mt * 16 + lr) * H1SH + kt * 32 + lg * 8);
          eacc[0][mt] = mfma16(ah, bh0, eacc[0][mt]);
          eacc[0][mt] = mfma16(al, bh0, eacc[0][mt]);
          eacc[0][mt] = mfma16(ah, bl0, eacc[0][mt]);
          eacc[1][mt] = mfma16(ah, bh1, eacc[1][mt]);
          eacc[1][mt] = mfma16(al, bh1, eacc[1][mt]);
          eacc[1][mt] = mfma16(ah, bl1, eacc[1][mt]);
        }
        bh0 = nbh0; bl0 = nbl0; bh1 = nbh1; bl1 = nbl1;
      }
    }
    __syncthreads();   // all h1 reads done before next chunk (or e epilogue) overwrites
  }

  // epilogue: +be2, split hi/lo into e planes (overwrites h1 region; barrier above covers)
#pragma unroll
  for (int g = 0; g < 2; ++g) {
    const int col = (w + g * 8) * 16 + lr;
    const float b2v = be2[col];
#pragma unroll
    for (int mt = 0; mt < 4; ++mt)
#pragma unroll
      for (int r = 0; r < 4; ++r) {
        const int row = mt * 16 + lg * 4 + r;
        const float v = eacc[g][mt][r] + b2v;
        const _Float16 h = (_Float16)v;
        eh[row * ESTH + col] = h;
        el[row * ESTH + col] = (_Float16)(v - (float)h);
      }
  }
  __syncthreads();

  // ================= phase 3: screened argmin over 512 codes =================
  // wave w: EXCLUSIVE codes [w*64, w*64+64) (nt = w*4+ntl), ALL 4 M-tiles.
  {
    float bd_[16];
    int   bi_[16];
#pragma unroll
    for (int s = 0; s < 16; ++s) { bd_[s] = 3.402823466e38f; bi_[s] = 0; }

#pragma unroll 1
    for (int ntl = 0; ntl < 4; ++ntl) {
      const int nt = w * 4 + ntl;
      f32x4 acc[4];
#pragma unroll
      for (int mt = 0; mt < 4; ++mt) acc[mt] = (f32x4){0.f, 0.f, 0.f, 0.f};
      const int fb = nt * 8 * 64 + lane;
      f16x8 bh = cbthf[fb], bl = cbtlf[fb];
#pragma unroll 1
      for (int kt = 0; kt < 8; ++kt) {
        const int ktn = (kt + 1 < 8) ? kt + 1 : kt;
        f16x8 nbh = cbthf[fb + ktn * 64], nbl = cbtlf[fb + ktn * 64];
#pragma unroll
        for (int mt = 0; mt < 4; ++mt) {
          f16x8 ah = *(const f16x8*)(eh + (mt * 16 + lr) * ESTH + kt * 32 + lg * 8);
          f16x8 al = *(const f16x8*)(el + (mt * 16 + lr) * ESTH + kt * 32 + lg * 8);
          acc[mt] = mfma16(ah, bh, acc[mt]);
          acc[mt] = mfma16(al, bh, acc[mt]);
          acc[mt] = mfma16(ah, bl, acc[mt]);
        }
        bh = nbh; bl = nbl;
      }
      const int code = nt * 16 + lr;
      const float nr = ls_nrm[code];
#pragma unroll
      for (int mt = 0; mt < 4; ++mt)
#pragma unroll
        for (int r = 0; r < 4; ++r) {
          const float d = fmaf(-2.f, acc[mt][r], nr);
          const int s = mt * 4 + r;
          const bool lt = d < bd_[s];       // strict < : first index wins ties
          bd_[s] = lt ? d : bd_[s];
          bi_[s] = lt ? code : bi_[s];
        }
    }
    // reduce across the 16-lane code dim (lr), lexicographic (d, idx)
#pragma unroll
    for (int off = 1; off < 16; off <<= 1) {
#pragma unroll
      for (int s = 0; s < 16; ++s) {
        const float od = __shfl_xor(bd_[s], off);
        const int   oi = __shfl_xor(bi_[s], off);
        const bool better = (od < bd_[s]) || (od == bd_[s] && oi < bi_[s]);
        bd_[s] = better ? od : bd_[s];
        bi_[s] = better ? oi : bi_[s];
      }
    }
    if (lr == 0) {
#pragma unroll
      for (int s = 0; s < 16; ++s) {
        const int token = (s >> 2) * 16 + lg * 4 + (s & 3);
        cand_d[token * 8 + w] = bd_[s];
        cand_i[token * 8 + w] = bi_[s];
      }
    }
  }
  __syncthreads();

  // fp32 recompute of the 8 wave-winners (exact e = hi+lo); jnp first-min pick
  {
    const int token = t >> 3, c = t & 7;
    int ci = cand_i[token * 8 + c];
    const float4* crow = (const float4*)(cb + ci * DIM);
    float s = 0.f;
#pragma unroll 4
    for (int k8 = 0; k8 < 32; ++k8) {
      f16x8 hv = *(const f16x8*)(eh + token * ESTH + k8 * 8);
      f16x8 lv = *(const f16x8*)(el + token * ESTH + k8 * 8);
      const float4 c0 = crow[k8 * 2];
      const float4 c1 = crow[k8 * 2 + 1];
      s = fmaf((float)hv[0] + (float)lv[0], c0.x, s);
      s = fmaf((float)hv[1] + (float)lv[1], c0.y, s);
      s = fmaf((float)hv[2] + (float)lv[2], c0.z, s);
      s = fmaf((float)hv[3] + (float)lv[3], c0.w, s);
      s = fmaf((float)hv[4] + (float)lv[4], c1.x, s);
      s = fmaf((float)hv[5] + (float)lv[5], c1.y, s);
      s = fmaf((float)hv[6] + (float)lv[6], c1.z, s);
      s = fmaf((float)hv[7] + (float)lv[7], c1.w, s);
    }
    float d = fmaf(-2.f, s, ls_nrm[ci]);
#pragma unroll
    for (int off = 1; off < 8; off <<= 1) {
      const float od = __shfl_xor(d, off);
      const int   oi = __shfl_xor(ci, off);
      const bool better = (od < d) || (od == d && oi < ci);
      d = better ? od : d;
      ci = better ? oi : ci;
    }
    if (c == 0) ls_idx[token] = ci;
  }
  __syncthreads();

  // gather q rows (pre-split planes) into e planes
  {
    const int token = t >> 3, part = t & 7;
    const u32x4* srch = (const u32x4*)(cbh + ls_idx[token] * DIM + part * 32);
    const u32x4* srcl = (const u32x4*)(cbl + ls_idx[token] * DIM + part * 32);
    u32x4* dsth = (u32x4*)(eh + token * ESTH + part * 32);
    u32x4* dstl = (u32x4*)(el + token * ESTH + part * 32);
#pragma unroll
    for (int i = 0; i < 4; ++i) { dsth[i] = srch[i]; dstl[i] = srcl[i]; }
  }
  __syncthreads();

  // ================= phase 4+5: out = relu(q@wd1+bd1) @ wd2 + bd2 =================
  // wave w: EXCLUSIVE N-tiles [w*8, w*8+8), ALL 4 M-tiles.
  {
    float op[16];
#pragma unroll
    for (int s = 0; s < 16; ++s) op[s] = 0.f;

#pragma unroll 1
    for (int ntl = 0; ntl < 8; ++ntl) {
      const int nt = w * 8 + ntl;
      f32x4 acc[4];
#pragma unroll
      for (int mt = 0; mt < 4; ++mt) acc[mt] = (f32x4){0.f, 0.f, 0.f, 0.f};
      const int fb = nt * 8 * 64 + lane;
      f16x8 bh = wd1hf[fb], bl = wd1lf[fb];
#pragma unroll 1
      for (int kt = 0; kt < 8; ++kt) {
        const int ktn = (kt + 1 < 8) ? kt + 1 : kt;
        f16x8 nbh = wd1hf[fb + ktn * 64], nbl = wd1lf[fb + ktn * 64];
#pragma unroll
        for (int mt = 0; mt < 4; ++mt) {
          f16x8 ah = *(const f16x8*)(eh + (mt * 16 + lr) * ESTH + kt * 32 + lg * 8);
          f16x8 al = *(const f16x8*)(el + (mt * 16 + lr) * ESTH + kt * 32 + lg * 8);
          acc[mt] = mfma16(ah, bh, acc[mt]);
          acc[mt] = mfma16(al, bh, acc[mt]);
          acc[mt] = mfma16(ah, bl, acc[mt]);
        }
        bh = nbh; bl = nbl;
      }
      const int col = nt * 16 + lr;
      const float b1v = bd1[col], w2v = wd2[col];
#pragma unroll
      for (int mt = 0; mt < 4; ++mt)
#pragma unroll
        for (int r = 0; r < 4; ++r) {
          const float h = fmaxf(acc[mt][r] + b1v, 0.f);
          op[mt * 4 + r] = fmaf(h, w2v, op[mt * 4 + r]);
        }
    }
    // reduce over the 16 hidden-col lanes
#pragma unroll
    for (int off = 1; off < 16; off <<= 1)
#pragma unroll
      for (int s = 0; s < 16; ++s) op[s] += __shfl_xor(op[s], off);
    if (lr == 0) {
#pragma unroll
      for (int s = 0; s < 16; ++s) {
        const int token = (s >> 2) * 16 + lg * 4 + (s & 3);
        ls_outp[token][w] = op[s];
      }
    }
  }
  __syncthreads();
  if (t < TILE_M) {
    float v = bd2[0];
#pragma unroll
    for (int c = 0; c < 8; ++c) v += ls_outp[t][c];
    out[tok0 + t] = v;
  }
}

extern "C" void kernel_launch(void* const* d_in, const int* in_sizes, int n_in,
                              void* d_out, int out_size, void* d_ws, size_t ws_size,
                              hipStream_t stream) {
  (void)in_sizes; (void)n_in; (void)out_size; (void)ws_size;
  const float* x   = (const float*)d_in[0];
  const float* we1 = (const float*)d_in[1];
  const float* be1 = (const float*)d_in[2];
  const float* we2 = (const float*)d_in[3];
  const float* be2 = (const float*)d_in[4];
  const float* cb  = (const float*)d_in[5];
  const float* wd1 = (const float*)d_in[6];
  const float* bd1 = (const float*)d_in[7];
  const float* wd2 = (const float*)d_in[8];
  const float* bd2 = (const float*)d_in[9];
  float* out = (float*)d_out;
  char* ws = (char*)d_ws;

  hipLaunchKernelGGL(prep_frags, dim3(320), dim3(256), 0, stream, we2, wd1, cb, ws);
  hipLaunchKernelGGL(prep_cb, dim3(NCB), dim3(64), 0, stream, cb, ws);
  hipLaunchKernelGGL(prep_we, dim3(4), dim3(256), 0, stream, we1, be1, ws);
  hipLaunchKernelGGL(vq_main, dim3(NTOK / TILE_M), dim3(BLOCK), 0, stream,
                     x, be2, cb, bd1, wd2, bd2, ws, out);
}

// Round 12
// 726.919 us; speedup vs baseline: 4.1109x; 1.0296x over previous
//
#include <hip/hip_runtime.h>

typedef unsigned int u32;
typedef __attribute__((ext_vector_type(8))) _Float16 f16x8;
typedef __attribute__((ext_vector_type(4))) _Float16 f16x4;
typedef __attribute__((ext_vector_type(4))) float    f32x4;
typedef __attribute__((ext_vector_type(4))) u32      u32x4;

constexpr int NTOK = 2048 * 64;
constexpr int HID  = 1024;
constexpr int DIM  = 256;
constexpr int NCB  = 512;

constexpr int TILE_M = 64;
constexpr int BLOCK  = 512;

// ---- workspace layout (bytes) ----
constexpr size_t OFF_WE2H = 0;            // 512 frags * 1KB
constexpr size_t OFF_WE2L = 512u << 10;
constexpr size_t OFF_WD1H = 1024u << 10;  // 512 frags
constexpr size_t OFF_WD1L = 1536u << 10;
constexpr size_t OFF_CBTH = 2048u << 10;  // 256 frags
constexpr size_t OFF_CBTL = 2304u << 10;
constexpr size_t OFF_CBH  = 2560u << 10;  // cb hi plane: 512*256 f16 = 256KB
constexpr size_t OFF_CBL  = 2816u << 10;  // cb lo plane
constexpr size_t OFF_NRM  = 3072u << 10;  // 512 f32
constexpr size_t OFF_WEPK = 3080u << 10;  // wepack: 1024 float4 = 16KB

// LDS strides in f16 units. Byte strides 528 / 272 -> 16B-slot quads spread
// 8 lanes/quad (balanced minimum) for the fragment read pattern.
constexpr int ESTH = 264;   // e/q plane row stride (256 + 8 pad)
constexpr int H1SH = 136;   // h1 plane row stride (128 + 8 pad)

__device__ inline f32x4 mfma16(f16x8 a, f16x8 b, f32x4 c) {
  return __builtin_amdgcn_mfma_f32_16x16x32_f16(a, b, c, 0, 0, 0);
}

// ======================= prep 1: fragment packing (HW-validated, unchanged) =======================
// B-frag convention (16x16x32): lane l holds B[kt*32 + (l>>4)*8 + j][nt*16 + (l&15)], j=0..7.
__global__ void prep_frags(const float* __restrict__ we2,
                           const float* __restrict__ wd1,
                           const float* __restrict__ cb,
                           char* __restrict__ ws) {
  int tid  = blockIdx.x * 256 + threadIdx.x;   // 1280 frags * 64 lanes
  int f    = tid >> 6;
  int lane = tid & 63;
  int lr = lane & 15, lg = lane >> 4;
  float v[8];
  _Float16 *dh, *dl;
  int fo;
  if (f < 512) {                // we2 (1024 x 256): f = nt*32 + kt
    int nt = f >> 5, kt = f & 31;
    int kb = kt * 32 + lg * 8, col = nt * 16 + lr;
#pragma unroll
    for (int j = 0; j < 8; ++j) v[j] = we2[(kb + j) * DIM + col];
    dh = (_Float16*)(ws + OFF_WE2H); dl = (_Float16*)(ws + OFF_WE2L); fo = f;
  } else if (f < 1024) {        // wd1 (256 x 1024): f = nt*8 + kt
    int fp = f - 512;
    int nt = fp >> 3, kt = fp & 7;
    int kb = kt * 32 + lg * 8, col = nt * 16 + lr;
#pragma unroll
    for (int j = 0; j < 8; ++j) v[j] = wd1[(kb + j) * HID + col];
    dh = (_Float16*)(ws + OFF_WD1H); dl = (_Float16*)(ws + OFF_WD1L); fo = fp;
  } else {                      // cbT: B[k][n] = cb[n][k]; f = nt*8 + kt
    int fp = f - 1024;
    int nt = fp >> 3, kt = fp & 7;
    const float* src = cb + (nt * 16 + lr) * DIM + kt * 32 + lg * 8;
#pragma unroll
    for (int j = 0; j < 8; ++j) v[j] = src[j];
    dh = (_Float16*)(ws + OFF_CBTH); dl = (_Float16*)(ws + OFF_CBTL); fo = fp;
  }
  f16x8 hv, lv;
#pragma unroll
  for (int j = 0; j < 8; ++j) {
    _Float16 h = (_Float16)v[j];
    hv[j] = h;
    lv[j] = (_Float16)(v[j] - (float)h);
  }
  ((f16x8*)dh)[fo * 64 + lane] = hv;
  ((f16x8*)dl)[fo * 64 + lane] = lv;
}

// ======================= prep 2: cb hi/lo planes + norms =======================
__global__ void prep_cb(const float* __restrict__ cb, char* __restrict__ ws) {
  int b = blockIdx.x;          // codebook row
  int l = threadIdx.x;         // 64 threads
  _Float16* cbh = (_Float16*)(ws + OFF_CBH);
  _Float16* cbl = (_Float16*)(ws + OFF_CBL);
  float*    nrm = (float*)(ws + OFF_NRM);
  float4 v = ((const float4*)(cb + b * DIM))[l];
  float s = (v.x * v.x + v.y * v.y) + (v.z * v.z + v.w * v.w);
#pragma unroll
  for (int off = 1; off < 64; off <<= 1) s += __shfl_xor(s, off);
  if (l == 0) nrm[b] = s;
  f16x4 hv, lv;
  float vv[4] = {v.x, v.y, v.z, v.w};
#pragma unroll
  for (int j = 0; j < 4; ++j) {
    _Float16 h = (_Float16)vv[j];
    hv[j] = h;
    lv[j] = (_Float16)(vv[j] - (float)h);
  }
  *(f16x4*)(cbh + b * DIM + l * 4) = hv;
  *(f16x4*)(cbl + b * DIM + l * 4) = lv;
}

// ======================= prep 3: encoder-L1 packed table =======================
// wepack[k] = (we1[0][k], we1[1][k], be1[k], 0) -> single load stream in staging.
__global__ void prep_we(const float* __restrict__ we1,
                        const float* __restrict__ be1,
                        char* __restrict__ ws) {
  int k = blockIdx.x * 256 + threadIdx.x;   // 1024
  float4* wp = (float4*)(ws + OFF_WEPK);
  float4 o; o.x = we1[k]; o.y = we1[HID + k]; o.z = be1[k]; o.w = 0.f;
  wp[k] = o;
}

// ======================= main fused kernel =======================
// __launch_bounds__(512, 4): 4 waves/EU -> unified reg cap 128/wave -> 2 blocks/CU.
// MFMA phases are kt-outer / mt-half passes / ntl-inner: one A-fragment read
// feeds 4 N-tiles (6 MFMA per ds_read_b128) -> LDS port no longer paces MFMA.
// Per-pass register peak budgeted < 128 unified (WRITE_SIZE is the spill tripwire).
__global__ __launch_bounds__(BLOCK, 4) void vq_main(
    const float* __restrict__ x,
    const float* __restrict__ be2,
    const float* __restrict__ cb,
    const float* __restrict__ bd1, const float* __restrict__ wd2,
    const float* __restrict__ bd2,
    const char* __restrict__ ws,
    float* __restrict__ out) {
  // 67584 B buffer: during phase 1+2 the front 34816 B holds the h1 hi/lo chunk
  // planes; afterwards the whole buffer holds the e (later q) hi/lo planes.
  __shared__ __align__(16) _Float16 ls_buf[33792];
  __shared__ float ls_nrm[NCB];          // 2048 B
  __shared__ float ls_x[TILE_M][2];
  __shared__ int   ls_idx[TILE_M];
  __shared__ float ls_outp[TILE_M][8];
  __shared__ float cand_d[TILE_M * 8];
  __shared__ int   cand_i[TILE_M * 8];

  _Float16* eh  = ls_buf;                 // e hi plane [64][264]
  _Float16* el  = ls_buf + 16896;         // e lo plane
  _Float16* h1h = ls_buf;                 // h1 hi chunk plane [64][136]
  _Float16* h1l = ls_buf + 8704;          // h1 lo chunk plane

  const f16x8* we2hf = (const f16x8*)(ws + OFF_WE2H);
  const f16x8* we2lf = (const f16x8*)(ws + OFF_WE2L);
  const f16x8* wd1hf = (const f16x8*)(ws + OFF_WD1H);
  const f16x8* wd1lf = (const f16x8*)(ws + OFF_WD1L);
  const f16x8* cbthf = (const f16x8*)(ws + OFF_CBTH);
  const f16x8* cbtlf = (const f16x8*)(ws + OFF_CBTL);
  const _Float16* cbh = (const _Float16*)(ws + OFF_CBH);
  const _Float16* cbl = (const _Float16*)(ws + OFF_CBL);
  const float* nrmg  = (const float*)(ws + OFF_NRM);
  const float4* wpk  = (const float4*)(ws + OFF_WEPK);

  const int t    = threadIdx.x;
  const int w    = t >> 6;       // wave 0..7
  const int lane = t & 63;
  const int lr   = lane & 15;    // MFMA col / A-row selector
  const int lg   = lane >> 4;    // MFMA k-group / row-group
  const int tok0 = blockIdx.x * TILE_M;

  ls_nrm[t] = nrmg[t];                       // 512 == BLOCK
  if (t < TILE_M * 2) ls_x[t >> 1][t & 1] = x[tok0 * 2 + t];
  __syncthreads();

  // ================= phase 1+2: e = relu(x@we1+be1) @ we2 + be2 =================
  // Wave w owns N-tiles {w, w+8} (exclusive). Per ch (K-chunk 128): stage h1, MFMA.
  f32x4 eacc[2][4];
#pragma unroll
  for (int g = 0; g < 2; ++g)
#pragma unroll
    for (int mt = 0; mt < 4; ++mt) eacc[g][mt] = (f32x4){0.f, 0.f, 0.f, 0.f};

  const int sm = t >> 3, sc0 = (t & 7) * 16;  // staging: row sm, 16 cols
  const float sx0 = ls_x[sm][0], sx1 = ls_x[sm][1];

#pragma unroll 1
  for (int ch = 0; ch < 8; ++ch) {
    {  // h1 chunk staging: packed stream, f16x8 stores (conflict-free pattern)
      const float4* wp = wpk + ch * 128 + sc0;
#pragma unroll 1
      for (int half = 0; half < 2; ++half) {
        f16x8 hv, lv;
#pragma unroll
        for (int j = 0; j < 8; ++j) {
          float4 p = wp[half * 8 + j];
          float v = fmaxf(fmaf(sx0, p.x, fmaf(sx1, p.y, p.z)), 0.f);
          _Float16 h = (_Float16)v;
          hv[j] = h;
          lv[j] = (_Float16)(v - (float)h);
        }
        *(f16x8*)(h1h + sm * H1SH + sc0 + half * 8) = hv;
        *(f16x8*)(h1l + sm * H1SH + sc0 + half * 8) = lv;
      }
    }
    __syncthreads();
    {  // MFMA: B dist-1 double-buffer over kt; A reloaded per (kt,mt) from LDS
      const int fb0 = (w * 32 + ch * 4) * 64 + lane;        // nt = w
      const int fb1 = ((w + 8) * 32 + ch * 4) * 64 + lane;  // nt = w+8
      f16x8 bh0 = we2hf[fb0], bl0 = we2lf[fb0];
      f16x8 bh1 = we2hf[fb1], bl1 = we2lf[fb1];
#pragma unroll 1
      for (int kt = 0; kt < 4; ++kt) {
        const int ktn = (kt + 1 < 4) ? kt + 1 : kt;
        f16x8 nbh0 = we2hf[fb0 + ktn * 64], nbl0 = we2lf[fb0 + ktn * 64];
        f16x8 nbh1 = we2hf[fb1 + ktn * 64], nbl1 = we2lf[fb1 + ktn * 64];
#pragma unroll
        for (int mt = 0; mt < 4; ++mt) {
          f16x8 ah = *(const f16x8*)(h1h + (mt * 16 + lr) * H1SH + kt * 32 + lg * 8);
          f16x8 al = *(const f16x8*)(h1l + (mt * 16 + lr) * H1SH + kt * 32 + lg * 8);
          eacc[0][mt] = mfma16(ah, bh0, eacc[0][mt]);
          eacc[0][mt] = mfma16(al, bh0, eacc[0][mt]);
          eacc[0][mt] = mfma16(ah, bl0, eacc[0][mt]);
          eacc[1][mt] = mfma16(ah, bh1, eacc[1][mt]);
          eacc[1][mt] = mfma16(al, bh1, eacc[1][mt]);
          eacc[1][mt] = mfma16(ah, bl1, eacc[1][mt]);
        }
        bh0 = nbh0; bl0 = nbl0; bh1 = nbh1; bl1 = nbl1;
      }
    }
    __syncthreads();   // all h1 reads done before next chunk (or e epilogue) overwrites
  }

  // epilogue: +be2, split hi/lo into e planes (overwrites h1 region; barrier above covers)
#pragma unroll
  for (int g = 0; g < 2; ++g) {
    const int col = (w + g * 8) * 16 + lr;
    const float b2v = be2[col];
#pragma unroll
    for (int mt = 0; mt < 4; ++mt)
#pragma unroll
      for (int r = 0; r < 4; ++r) {
        const int row = mt * 16 + lg * 4 + r;
        const float v = eacc[g][mt][r] + b2v;
        const _Float16 h = (_Float16)v;
        eh[row * ESTH + col] = h;
        el[row * ESTH + col] = (_Float16)(v - (float)h);
      }
  }
  __syncthreads();

  // ================= phase 3: screened argmin over 512 codes =================
  // wave w: EXCLUSIVE codes [w*64, w*64+64). Two mt-half passes; kt-outer,
  // ntl-inner: 4 A-reads feed 24 MFMA per kt.
#pragma unroll 1
  for (int mh = 0; mh < 2; ++mh) {
    f32x4 acc[4][2];
#pragma unroll
    for (int ntl = 0; ntl < 4; ++ntl)
#pragma unroll
      for (int m2 = 0; m2 < 2; ++m2) acc[ntl][m2] = (f32x4){0.f, 0.f, 0.f, 0.f};

#pragma unroll 1
    for (int kt = 0; kt < 8; ++kt) {
      f16x8 ah[2], al[2];
#pragma unroll
      for (int m2 = 0; m2 < 2; ++m2) {
        const int mt = mh * 2 + m2;
        ah[m2] = *(const f16x8*)(eh + (mt * 16 + lr) * ESTH + kt * 32 + lg * 8);
        al[m2] = *(const f16x8*)(el + (mt * 16 + lr) * ESTH + kt * 32 + lg * 8);
      }
#pragma unroll
      for (int ntl = 0; ntl < 4; ++ntl) {
        const int fidx = ((w * 4 + ntl) * 8 + kt) * 64 + lane;
        f16x8 bh = cbthf[fidx];
        f16x8 bl = cbtlf[fidx];
#pragma unroll
        for (int m2 = 0; m2 < 2; ++m2) {
          acc[ntl][m2] = mfma16(ah[m2], bh, acc[ntl][m2]);
          acc[ntl][m2] = mfma16(al[m2], bh, acc[ntl][m2]);
          acc[ntl][m2] = mfma16(ah[m2], bl, acc[ntl][m2]);
        }
      }
    }
    // tracking (codes ascend with ntl; strict < keeps first index)
    float bd_[8];
    int   bi_[8];
#pragma unroll
    for (int s = 0; s < 8; ++s) { bd_[s] = 3.402823466e38f; bi_[s] = 0; }
#pragma unroll
    for (int ntl = 0; ntl < 4; ++ntl) {
      const int code = (w * 4 + ntl) * 16 + lr;
      const float nr = ls_nrm[code];
#pragma unroll
      for (int m2 = 0; m2 < 2; ++m2)
#pragma unroll
        for (int r = 0; r < 4; ++r) {
          const float d = fmaf(-2.f, acc[ntl][m2][r], nr);
          const int s = m2 * 4 + r;
          const bool lt = d < bd_[s];
          bd_[s] = lt ? d : bd_[s];
          bi_[s] = lt ? code : bi_[s];
        }
    }
    // reduce across the 16-lane code dim (lr), lexicographic (d, idx)
#pragma unroll
    for (int off = 1; off < 16; off <<= 1) {
#pragma unroll
      for (int s = 0; s < 8; ++s) {
        const float od = __shfl_xor(bd_[s], off);
        const int   oi = __shfl_xor(bi_[s], off);
        const bool better = (od < bd_[s]) || (od == bd_[s] && oi < bi_[s]);
        bd_[s] = better ? od : bd_[s];
        bi_[s] = better ? oi : bi_[s];
      }
    }
    if (lr == 0) {
#pragma unroll
      for (int s = 0; s < 8; ++s) {
        const int token = (mh * 2 + (s >> 2)) * 16 + lg * 4 + (s & 3);
        cand_d[token * 8 + w] = bd_[s];
        cand_i[token * 8 + w] = bi_[s];
      }
    }
  }
  __syncthreads();

  // fp32 recompute of the 8 wave-winners (exact e = hi+lo); jnp first-min pick
  {
    const int token = t >> 3, c = t & 7;
    int ci = cand_i[token * 8 + c];
    const float4* crow = (const float4*)(cb + ci * DIM);
    float s = 0.f;
#pragma unroll 4
    for (int k8 = 0; k8 < 32; ++k8) {
      f16x8 hv = *(const f16x8*)(eh + token * ESTH + k8 * 8);
      f16x8 lv = *(const f16x8*)(el + token * ESTH + k8 * 8);
      const float4 c0 = crow[k8 * 2];
      const float4 c1 = crow[k8 * 2 + 1];
      s = fmaf((float)hv[0] + (float)lv[0], c0.x, s);
      s = fmaf((float)hv[1] + (float)lv[1], c0.y, s);
      s = fmaf((float)hv[2] + (float)lv[2], c0.z, s);
      s = fmaf((float)hv[3] + (float)lv[3], c0.w, s);
      s = fmaf((float)hv[4] + (float)lv[4], c1.x, s);
      s = fmaf((float)hv[5] + (float)lv[5], c1.y, s);
      s = fmaf((float)hv[6] + (float)lv[6], c1.z, s);
      s = fmaf((float)hv[7] + (float)lv[7], c1.w, s);
    }
    float d = fmaf(-2.f, s, ls_nrm[ci]);
#pragma unroll
    for (int off = 1; off < 8; off <<= 1) {
      const float od = __shfl_xor(d, off);
      const int   oi = __shfl_xor(ci, off);
      const bool better = (od < d) || (od == d && oi < ci);
      d = better ? od : d;
      ci = better ? oi : ci;
    }
    if (c == 0) ls_idx[token] = ci;
  }
  __syncthreads();

  // gather q rows (pre-split planes) into e planes
  {
    const int token = t >> 3, part = t & 7;
    const u32x4* srch = (const u32x4*)(cbh + ls_idx[token] * DIM + part * 32);
    const u32x4* srcl = (const u32x4*)(cbl + ls_idx[token] * DIM + part * 32);
    u32x4* dsth = (u32x4*)(eh + token * ESTH + part * 32);
    u32x4* dstl = (u32x4*)(el + token * ESTH + part * 32);
#pragma unroll
    for (int i = 0; i < 4; ++i) { dsth[i] = srch[i]; dstl[i] = srcl[i]; }
  }
  __syncthreads();

  // ================= phase 4+5: out = relu(q@wd1+bd1) @ wd2 + bd2 =================
  // wave w: EXCLUSIVE N-tiles [w*8, w*8+8). mt-half x nt-half subpasses;
  // kt-outer, ntl-inner: 4 A-reads feed 24 MFMA per kt.
#pragma unroll 1
  for (int mh = 0; mh < 2; ++mh) {
    float op[8];
#pragma unroll
    for (int s = 0; s < 8; ++s) op[s] = 0.f;

#pragma unroll 1
    for (int nh = 0; nh < 2; ++nh) {
      f32x4 acc[4][2];
#pragma unroll
      for (int ntl = 0; ntl < 4; ++ntl)
#pragma unroll
        for (int m2 = 0; m2 < 2; ++m2) acc[ntl][m2] = (f32x4){0.f, 0.f, 0.f, 0.f};

#pragma unroll 1
      for (int kt = 0; kt < 8; ++kt) {
        f16x8 ah[2], al[2];
#pragma unroll
        for (int m2 = 0; m2 < 2; ++m2) {
          const int mt = mh * 2 + m2;
          ah[m2] = *(const f16x8*)(eh + (mt * 16 + lr) * ESTH + kt * 32 + lg * 8);
          al[m2] = *(const f16x8*)(el + (mt * 16 + lr) * ESTH + kt * 32 + lg * 8);
        }
#pragma unroll
        for (int ntl = 0; ntl < 4; ++ntl) {
          const int nt = w * 8 + nh * 4 + ntl;
          const int fidx = (nt * 8 + kt) * 64 + lane;
          f16x8 bh = wd1hf[fidx];
          f16x8 bl = wd1lf[fidx];
#pragma unroll
          for (int m2 = 0; m2 < 2; ++m2) {
            acc[ntl][m2] = mfma16(ah[m2], bh, acc[ntl][m2]);
            acc[ntl][m2] = mfma16(al[m2], bh, acc[ntl][m2]);
            acc[ntl][m2] = mfma16(ah[m2], bl, acc[ntl][m2]);
          }
        }
      }
      // fold this nt-half into op
#pragma unroll
      for (int ntl = 0; ntl < 4; ++ntl) {
        const int col = (w * 8 + nh * 4 + ntl) * 16 + lr;
        const float b1v = bd1[col], w2v = wd2[col];
#pragma unroll
        for (int m2 = 0; m2 < 2; ++m2)
#pragma unroll
          for (int r = 0; r < 4; ++r) {
            const float h = fmaxf(acc[ntl][m2][r] + b1v, 0.f);
            op[m2 * 4 + r] = fmaf(h, w2v, op[m2 * 4 + r]);
          }
      }
    }
    // reduce over the 16 hidden-col lanes
#pragma unroll
    for (int off = 1; off < 16; off <<= 1)
#pragma unroll
      for (int s = 0; s < 8; ++s) op[s] += __shfl_xor(op[s], off);
    if (lr == 0) {
#pragma unroll
      for (int s = 0; s < 8; ++s) {
        const int token = (mh * 2 + (s >> 2)) * 16 + lg * 4 + (s & 3);
        ls_outp[token][w] = op[s];
      }
    }
  }
  __syncthreads();
  if (t < TILE_M) {
    float v = bd2[0];
#pragma unroll
    for (int c = 0; c < 8; ++c) v += ls_outp[t][c];
    out[tok0 + t] = v;
  }
}

extern "C" void kernel_launch(void* const* d_in, const int* in_sizes, int n_in,
                              void* d_out, int out_size, void* d_ws, size_t ws_size,
                              hipStream_t stream) {
  (void)in_sizes; (void)n_in; (void)out_size; (void)ws_size;
  const float* x   = (const float*)d_in[0];
  const float* we1 = (const float*)d_in[1];
  const float* be1 = (const float*)d_in[2];
  const float* we2 = (const float*)d_in[3];
  const float* be2 = (const float*)d_in[4];
  const float* cb  = (const float*)d_in[5];
  const float* wd1 = (const float*)d_in[6];
  const float* bd1 = (const float*)d_in[7];
  const float* wd2 = (const float*)d_in[8];
  const float* bd2 = (const float*)d_in[9];
  float* out = (float*)d_out;
  char* ws = (char*)d_ws;

  hipLaunchKernelGGL(prep_frags, dim3(320), dim3(256), 0, stream, we2, wd1, cb, ws);
  hipLaunchKernelGGL(prep_cb, dim3(NCB), dim3(64), 0, stream, cb, ws);
  hipLaunchKernelGGL(prep_we, dim3(4), dim3(256), 0, stream, we1, be1, ws);
  hipLaunchKernelGGL(vq_main, dim3(NTOK / TILE_M), dim3(BLOCK), 0, stream,
                     x, be2, cb, bd1, wd2, bd2, ws, out);
}

// Round 14
// 667.640 us; speedup vs baseline: 4.4759x; 1.0888x over previous
//
#include <hip/hip_runtime.h>

typedef unsigned int u32;
typedef __attribute__((ext_vector_type(8))) _Float16 f16x8;
typedef __attribute__((ext_vector_type(4))) _Float16 f16x4;
typedef __attribute__((ext_vector_type(4))) float    f32x4;
typedef __attribute__((ext_vector_type(4))) u32      u32x4;

constexpr int NTOK = 2048 * 64;
constexpr int HID  = 1024;
constexpr int DIM  = 256;
constexpr int NCB  = 512;

constexpr int TILE_M = 64;
constexpr int BLOCK  = 512;

// ---- workspace layout (bytes) ----
constexpr size_t OFF_WE2H = 0;            // 512 frags * 1KB
constexpr size_t OFF_WE2L = 512u << 10;
constexpr size_t OFF_WD1H = 1024u << 10;  // 512 frags
constexpr size_t OFF_WD1L = 1536u << 10;  // (unused by vq_main since r13; kept for prep simplicity)
constexpr size_t OFF_CBTH = 2048u << 10;  // 256 frags
constexpr size_t OFF_CBTL = 2304u << 10;
constexpr size_t OFF_CBH  = 2560u << 10;  // cb hi plane: 512*256 f16 = 256KB
constexpr size_t OFF_CBL  = 2816u << 10;  // cb lo plane
constexpr size_t OFF_NRM  = 3072u << 10;  // 512 f32
constexpr size_t OFF_WEPK = 3080u << 10;  // wepack: 1024 float4 = 16KB

// LDS strides in f16 units. Byte strides 528 / 272 -> 16B-slot quads spread
// 8 lanes/quad (balanced minimum) for the fragment read pattern.
constexpr int ESTH = 264;   // e/q plane row stride (256 + 8 pad)
constexpr int H1SH = 136;   // h1 plane row stride (128 + 8 pad)
constexpr int H1BUF = 17408; // one h1 dbuf slot: hi[64][136] + lo[64][136] f16

__device__ inline f32x4 mfma16(f16x8 a, f16x8 b, f32x4 c) {
  return __builtin_amdgcn_mfma_f32_16x16x32_f16(a, b, c, 0, 0, 0);
}

// ======================= prep 1: fragment packing (HW-validated, unchanged) =======================
// B-frag convention (16x16x32): lane l holds B[kt*32 + (l>>4)*8 + j][nt*16 + (l&15)], j=0..7.
__global__ void prep_frags(const float* __restrict__ we2,
                           const float* __restrict__ wd1,
                           const float* __restrict__ cb,
                           char* __restrict__ ws) {
  int tid  = blockIdx.x * 256 + threadIdx.x;   // 1280 frags * 64 lanes
  int f    = tid >> 6;
  int lane = tid & 63;
  int lr = lane & 15, lg = lane >> 4;
  float v[8];
  _Float16 *dh, *dl;
  int fo;
  if (f < 512) {                // we2 (1024 x 256): f = nt*32 + kt
    int nt = f >> 5, kt = f & 31;
    int kb = kt * 32 + lg * 8, col = nt * 16 + lr;
#pragma unroll
    for (int j = 0; j < 8; ++j) v[j] = we2[(kb + j) * DIM + col];
    dh = (_Float16*)(ws + OFF_WE2H); dl = (_Float16*)(ws + OFF_WE2L); fo = f;
  } else if (f < 1024) {        // wd1 (256 x 1024): f = nt*8 + kt
    int fp = f - 512;
    int nt = fp >> 3, kt = fp & 7;
    int kb = kt * 32 + lg * 8, col = nt * 16 + lr;
#pragma unroll
    for (int j = 0; j < 8; ++j) v[j] = wd1[(kb + j) * HID + col];
    dh = (_Float16*)(ws + OFF_WD1H); dl = (_Float16*)(ws + OFF_WD1L); fo = fp;
  } else {                      // cbT: B[k][n] = cb[n][k]; f = nt*8 + kt
    int fp = f - 1024;
    int nt = fp >> 3, kt = fp & 7;
    const float* src = cb + (nt * 16 + lr) * DIM + kt * 32 + lg * 8;
#pragma unroll
    for (int j = 0; j < 8; ++j) v[j] = src[j];
    dh = (_Float16*)(ws + OFF_CBTH); dl = (_Float16*)(ws + OFF_CBTL); fo = fp;
  }
  f16x8 hv, lv;
#pragma unroll
  for (int j = 0; j < 8; ++j) {
    _Float16 h = (_Float16)v[j];
    hv[j] = h;
    lv[j] = (_Float16)(v[j] - (float)h);
  }
  ((f16x8*)dh)[fo * 64 + lane] = hv;
  ((f16x8*)dl)[fo * 64 + lane] = lv;
}

// ======================= prep 2: cb hi/lo planes + norms =======================
__global__ void prep_cb(const float* __restrict__ cb, char* __restrict__ ws) {
  int b = blockIdx.x;          // codebook row
  int l = threadIdx.x;         // 64 threads
  _Float16* cbh = (_Float16*)(ws + OFF_CBH);
  _Float16* cbl = (_Float16*)(ws + OFF_CBL);
  float*    nrm = (float*)(ws + OFF_NRM);
  float4 v = ((const float4*)(cb + b * DIM))[l];
  float s = (v.x * v.x + v.y * v.y) + (v.z * v.z + v.w * v.w);
#pragma unroll
  for (int off = 1; off < 64; off <<= 1) s += __shfl_xor(s, off);
  if (l == 0) nrm[b] = s;
  f16x4 hv, lv;
  float vv[4] = {v.x, v.y, v.z, v.w};
#pragma unroll
  for (int j = 0; j < 4; ++j) {
    _Float16 h = (_Float16)vv[j];
    hv[j] = h;
    lv[j] = (_Float16)(vv[j] - (float)h);
  }
  *(f16x4*)(cbh + b * DIM + l * 4) = hv;
  *(f16x4*)(cbl + b * DIM + l * 4) = lv;
}

// ======================= prep 3: encoder-L1 packed table =======================
// wepack[k] = (we1[0][k], we1[1][k], be1[k], 0) -> single load stream in staging.
__global__ void prep_we(const float* __restrict__ we1,
                        const float* __restrict__ be1,
                        char* __restrict__ ws) {
  int k = blockIdx.x * 256 + threadIdx.x;   // 1024
  float4* wp = (float4*)(ws + OFF_WEPK);
  float4 o; o.x = we1[k]; o.y = we1[HID + k]; o.z = be1[k]; o.w = 0.f;
  wp[k] = o;
}

// stage h1 chunk CH into dbuf slot B (hi/lo f16 planes), f16x8 stores
#define STAGE_H1(B, CH)                                                 \
  {                                                                     \
    const float4* wp_ = wpk + (CH) * 128 + sc0;                         \
    _Float16* dh_ = ls_buf + (B) * H1BUF + sm * H1SH + sc0;             \
    _Float16* dl_ = dh_ + 8704;                                         \
    _Pragma("unroll 1")                                                 \
    for (int half_ = 0; half_ < 2; ++half_) {                           \
      f16x8 hv_, lv_;                                                   \
      _Pragma("unroll")                                                 \
      for (int j_ = 0; j_ < 8; ++j_) {                                  \
        float4 p_ = wp_[half_ * 8 + j_];                                \
        float v_ = fmaxf(fmaf(sx0, p_.x, fmaf(sx1, p_.y, p_.z)), 0.f);  \
        _Float16 h_ = (_Float16)v_;                                     \
        hv_[j_] = h_;                                                   \
        lv_[j_] = (_Float16)(v_ - (float)h_);                           \
      }                                                                 \
      *(f16x8*)(dh_ + half_ * 8) = hv_;                                 \
      *(f16x8*)(dl_ + half_ * 8) = lv_;                                 \
    }                                                                   \
  }

// ======================= main fused kernel =======================
// __launch_bounds__(512, 4): 4 waves/EU -> unified reg cap 128/wave -> 2 blocks/CU.
// r13 changes: (1) phase-1 h1 double-buffer pipeline, ONE barrier per chunk
// (stage ch+1 issues under MFMA on ch); (2) decoder (phase 4+5) is pure fp16
// (1 MFMA/product, hi planes only) -- error ~7e-4 << 0.021; argmin path
// (3-MFMA screen + exact-fp32 recompute) untouched, so idx is unchanged.
__global__ __launch_bounds__(BLOCK, 4) void vq_main(
    const float* __restrict__ x,
    const float* __restrict__ be2,
    const float* __restrict__ cb,
    const float* __restrict__ bd1, const float* __restrict__ wd2,
    const float* __restrict__ bd2,
    const char* __restrict__ ws,
    float* __restrict__ out) {
  // 69632 B buffer: phase 1+2 uses it as two h1 dbuf slots (hi+lo each);
  // afterwards it holds the e (later q) hi/lo planes.
  __shared__ __align__(16) _Float16 ls_buf[2 * H1BUF];
  __shared__ float ls_nrm[NCB];          // 2048 B
  __shared__ float ls_x[TILE_M][2];
  __shared__ int   ls_idx[TILE_M];
  __shared__ float ls_outp[TILE_M][8];
  __shared__ float cand_d[TILE_M * 8];
  __shared__ int   cand_i[TILE_M * 8];

  _Float16* eh  = ls_buf;                 // e hi plane [64][264]
  _Float16* el  = ls_buf + 16896;         // e lo plane

  const f16x8* we2hf = (const f16x8*)(ws + OFF_WE2H);
  const f16x8* we2lf = (const f16x8*)(ws + OFF_WE2L);
  const f16x8* wd1hf = (const f16x8*)(ws + OFF_WD1H);
  const f16x8* cbthf = (const f16x8*)(ws + OFF_CBTH);
  const f16x8* cbtlf = (const f16x8*)(ws + OFF_CBTL);
  const _Float16* cbh = (const _Float16*)(ws + OFF_CBH);
  const _Float16* cbl = (const _Float16*)(ws + OFF_CBL);
  const float* nrmg  = (const float*)(ws + OFF_NRM);
  const float4* wpk  = (const float4*)(ws + OFF_WEPK);

  const int t    = threadIdx.x;
  const int w    = t >> 6;       // wave 0..7
  const int lane = t & 63;
  const int lr   = lane & 15;    // MFMA col / A-row selector
  const int lg   = lane >> 4;    // MFMA k-group / row-group
  const int tok0 = blockIdx.x * TILE_M;

  ls_nrm[t] = nrmg[t];                       // 512 == BLOCK
  if (t < TILE_M * 2) ls_x[t >> 1][t & 1] = x[tok0 * 2 + t];
  __syncthreads();

  // ================= phase 1+2: e = relu(x@we1+be1) @ we2 + be2 =================
  // Wave w owns N-tiles {w, w+8}. Pipelined: stage(ch+1 into buf^1) under
  // MFMA(buf), single barrier per chunk.
  f32x4 eacc[2][4];
#pragma unroll
  for (int g = 0; g < 2; ++g)
#pragma unroll
    for (int mt = 0; mt < 4; ++mt) eacc[g][mt] = (f32x4){0.f, 0.f, 0.f, 0.f};

  const int sm = t >> 3, sc0 = (t & 7) * 16;  // staging: row sm, 16 cols
  const float sx0 = ls_x[sm][0], sx1 = ls_x[sm][1];

  STAGE_H1(0, 0);
  __syncthreads();

#pragma unroll 1
  for (int ch = 0; ch < 8; ++ch) {
    const int cur = ch & 1;
    if (ch < 7) STAGE_H1(cur ^ 1, ch + 1);   // issue next chunk under this MFMA
    const _Float16* h1hp = ls_buf + cur * H1BUF;
    const _Float16* h1lp = h1hp + 8704;
    {  // MFMA: B dist-1 double-buffer over kt; A reloaded per (kt,mt) from LDS
      const int fb0 = (w * 32 + ch * 4) * 64 + lane;        // nt = w
      const int fb1 = ((w + 8) * 32 + ch * 4) * 64 + lane;  // nt = w+8
      f16x8 bh0 = we2hf[fb0], bl0 = we2lf[fb0];
      f16x8 bh1 = we2hf[fb1], bl1 = we2lf[fb1];
#pragma unroll 1
      for (int kt = 0; kt < 4; ++kt) {
        const int ktn = (kt + 1 < 4) ? kt + 1 : kt;
        f16x8 nbh0 = we2hf[fb0 + ktn * 64], nbl0 = we2lf[fb0 + ktn * 64];
        f16x8 nbh1 = we2hf[fb1 + ktn * 64], nbl1 = we2lf[fb1 + ktn * 64];
#pragma unroll
        for (int mt = 0; mt < 4; ++mt) {
          f16x8 ah = *(const f16x8*)(h1hp + (mt * 16 + lr) * H1SH + kt * 32 + lg * 8);
          f16x8 al = *(const f16x8*)(h1lp + (mt * 16 + lr) * H1SH + kt * 32 + lg * 8);
          eacc[0][mt] = mfma16(ah, bh0, eacc[0][mt]);
          eacc[0][mt] = mfma16(al, bh0, eacc[0][mt]);
          eacc[0][mt] = mfma16(ah, bl0, eacc[0][mt]);
          eacc[1][mt] = mfma16(ah, bh1, eacc[1][mt]);
          eacc[1][mt] = mfma16(al, bh1, eacc[1][mt]);
          eacc[1][mt] = mfma16(ah, bl1, eacc[1][mt]);
        }
        bh0 = nbh0; bl0 = nbl0; bh1 = nbh1; bl1 = nbl1;
      }
    }
    __syncthreads();   // staged ch+1 visible; all reads of buf done before it is re-staged
  }

  // epilogue: +be2, split hi/lo into e planes (overwrites h1 region; barrier above covers)
#pragma unroll
  for (int g = 0; g < 2; ++g) {
    const int col = (w + g * 8) * 16 + lr;
    const float b2v = be2[col];
#pragma unroll
    for (int mt = 0; mt < 4; ++mt)
#pragma unroll
      for (int r = 0; r < 4; ++r) {
        const int row = mt * 16 + lg * 4 + r;
        const float v = eacc[g][mt][r] + b2v;
        const _Float16 h = (_Float16)v;
        eh[row * ESTH + col] = h;
        el[row * ESTH + col] = (_Float16)(v - (float)h);
      }
  }
  __syncthreads();

  // ================= phase 3: screened argmin over 512 codes =================
  // wave w: EXCLUSIVE codes [w*64, w*64+64). Two mt-half passes; kt-outer,
  // ntl-inner: 4 A-reads feed 24 MFMA per kt. Full 3-MFMA precision (argmin).
#pragma unroll 1
  for (int mh = 0; mh < 2; ++mh) {
    f32x4 acc[4][2];
#pragma unroll
    for (int ntl = 0; ntl < 4; ++ntl)
#pragma unroll
      for (int m2 = 0; m2 < 2; ++m2) acc[ntl][m2] = (f32x4){0.f, 0.f, 0.f, 0.f};

#pragma unroll 1
    for (int kt = 0; kt < 8; ++kt) {
      f16x8 ah[2], al[2];
#pragma unroll
      for (int m2 = 0; m2 < 2; ++m2) {
        const int mt = mh * 2 + m2;
        ah[m2] = *(const f16x8*)(eh + (mt * 16 + lr) * ESTH + kt * 32 + lg * 8);
        al[m2] = *(const f16x8*)(el + (mt * 16 + lr) * ESTH + kt * 32 + lg * 8);
      }
#pragma unroll
      for (int ntl = 0; ntl < 4; ++ntl) {
        const int fidx = ((w * 4 + ntl) * 8 + kt) * 64 + lane;
        f16x8 bh = cbthf[fidx];
        f16x8 bl = cbtlf[fidx];
#pragma unroll
        for (int m2 = 0; m2 < 2; ++m2) {
          acc[ntl][m2] = mfma16(ah[m2], bh, acc[ntl][m2]);
          acc[ntl][m2] = mfma16(al[m2], bh, acc[ntl][m2]);
          acc[ntl][m2] = mfma16(ah[m2], bl, acc[ntl][m2]);
        }
      }
    }
    // tracking (codes ascend with ntl; strict < keeps first index)
    float bd_[8];
    int   bi_[8];
#pragma unroll
    for (int s = 0; s < 8; ++s) { bd_[s] = 3.402823466e38f; bi_[s] = 0; }
#pragma unroll
    for (int ntl = 0; ntl < 4; ++ntl) {
      const int code = (w * 4 + ntl) * 16 + lr;
      const float nr = ls_nrm[code];
#pragma unroll
      for (int m2 = 0; m2 < 2; ++m2)
#pragma unroll
        for (int r = 0; r < 4; ++r) {
          const float d = fmaf(-2.f, acc[ntl][m2][r], nr);
          const int s = m2 * 4 + r;
          const bool lt = d < bd_[s];
          bd_[s] = lt ? d : bd_[s];
          bi_[s] = lt ? code : bi_[s];
        }
    }
    // reduce across the 16-lane code dim (lr), lexicographic (d, idx)
#pragma unroll
    for (int off = 1; off < 16; off <<= 1) {
#pragma unroll
      for (int s = 0; s < 8; ++s) {
        const float od = __shfl_xor(bd_[s], off);
        const int   oi = __shfl_xor(bi_[s], off);
        const bool better = (od < bd_[s]) || (od == bd_[s] && oi < bi_[s]);
        bd_[s] = better ? od : bd_[s];
        bi_[s] = better ? oi : bi_[s];
      }
    }
    if (lr == 0) {
#pragma unroll
      for (int s = 0; s < 8; ++s) {
        const int token = (mh * 2 + (s >> 2)) * 16 + lg * 4 + (s & 3);
        cand_d[token * 8 + w] = bd_[s];
        cand_i[token * 8 + w] = bi_[s];
      }
    }
  }
  __syncthreads();

  // fp32 recompute of the 8 wave-winners (exact e = hi+lo); jnp first-min pick
  {
    const int token = t >> 3, c = t & 7;
    int ci = cand_i[token * 8 + c];
    const float4* crow = (const float4*)(cb + ci * DIM);
    float s = 0.f;
#pragma unroll 4
    for (int k8 = 0; k8 < 32; ++k8) {
      f16x8 hv = *(const f16x8*)(eh + token * ESTH + k8 * 8);
      f16x8 lv = *(const f16x8*)(el + token * ESTH + k8 * 8);
      const float4 c0 = crow[k8 * 2];
      const float4 c1 = crow[k8 * 2 + 1];
      s = fmaf((float)hv[0] + (float)lv[0], c0.x, s);
      s = fmaf((float)hv[1] + (float)lv[1], c0.y, s);
      s = fmaf((float)hv[2] + (float)lv[2], c0.z, s);
      s = fmaf((float)hv[3] + (float)lv[3], c0.w, s);
      s = fmaf((float)hv[4] + (float)lv[4], c1.x, s);
      s = fmaf((float)hv[5] + (float)lv[5], c1.y, s);
      s = fmaf((float)hv[6] + (float)lv[6], c1.z, s);
      s = fmaf((float)hv[7] + (float)lv[7], c1.w, s);
    }
    float d = fmaf(-2.f, s, ls_nrm[ci]);
#pragma unroll
    for (int off = 1; off < 8; off <<= 1) {
      const float od = __shfl_xor(d, off);
      const int   oi = __shfl_xor(ci, off);
      const bool better = (od < d) || (od == d && oi < ci);
      d = better ? od : d;
      ci = better ? oi : ci;
    }
    if (c == 0) ls_idx[token] = ci;
  }
  __syncthreads();

  // gather q rows into the hi plane only (decoder is pure fp16 now)
  {
    const int token = t >> 3, part = t & 7;
    const u32x4* srch = (const u32x4*)(cbh + ls_idx[token] * DIM + part * 32);
    u32x4* dsth = (u32x4*)(eh + token * ESTH + part * 32);
#pragma unroll
    for (int i = 0; i < 4; ++i) dsth[i] = srch[i];
  }
  __syncthreads();

  // ================= phase 4+5: out = relu(q@wd1+bd1) @ wd2 + bd2 =================
  // Pure fp16 (hi planes, 1 MFMA/product): decoder error ~7e-4 << 0.021 and
  // cannot affect argmin (q gathered exactly; only idx feeds the decoder).
#pragma unroll 1
  for (int mh = 0; mh < 2; ++mh) {
    float op[8];
#pragma unroll
    for (int s = 0; s < 8; ++s) op[s] = 0.f;

#pragma unroll 1
    for (int nh = 0; nh < 2; ++nh) {
      f32x4 acc[4][2];
#pragma unroll
      for (int ntl = 0; ntl < 4; ++ntl)
#pragma unroll
        for (int m2 = 0; m2 < 2; ++m2) acc[ntl][m2] = (f32x4){0.f, 0.f, 0.f, 0.f};

#pragma unroll 1
      for (int kt = 0; kt < 8; ++kt) {
        f16x8 ah[2];
#pragma unroll
        for (int m2 = 0; m2 < 2; ++m2) {
          const int mt = mh * 2 + m2;
          ah[m2] = *(const f16x8*)(eh + (mt * 16 + lr) * ESTH + kt * 32 + lg * 8);
        }
#pragma unroll
        for (int ntl = 0; ntl < 4; ++ntl) {
          const int nt = w * 8 + nh * 4 + ntl;
          const int fidx = (nt * 8 + kt) * 64 + lane;
          f16x8 bh = wd1hf[fidx];
#pragma unroll
          for (int m2 = 0; m2 < 2; ++m2)
            acc[ntl][m2] = mfma16(ah[m2], bh, acc[ntl][m2]);
        }
      }
      // fold this nt-half into op
#pragma unroll
      for (int ntl = 0; ntl < 4; ++ntl) {
        const int col = (w * 8 + nh * 4 + ntl) * 16 + lr;
        const float b1v = bd1[col], w2v = wd2[col];
#pragma unroll
        for (int m2 = 0; m2 < 2; ++m2)
#pragma unroll
          for (int r = 0; r < 4; ++r) {
            const float h = fmaxf(acc[ntl][m2][r] + b1v, 0.f);
            op[m2 * 4 + r] = fmaf(h, w2v, op[m2 * 4 + r]);
          }
      }
    }
    // reduce over the 16 hidden-col lanes
#pragma unroll
    for (int off = 1; off < 16; off <<= 1)
#pragma unroll
      for (int s = 0; s < 8; ++s) op[s] += __shfl_xor(op[s], off);
    if (lr == 0) {
#pragma unroll
      for (int s = 0; s < 8; ++s) {
        const int token = (mh * 2 + (s >> 2)) * 16 + lg * 4 + (s & 3);
        ls_outp[token][w] = op[s];
      }
    }
  }
  __syncthreads();
  if (t < TILE_M) {
    float v = bd2[0];
#pragma unroll
    for (int c = 0; c < 8; ++c) v += ls_outp[t][c];
    out[tok0 + t] = v;
  }
}

extern "C" void kernel_launch(void* const* d_in, const int* in_sizes, int n_in,
                              void* d_out, int out_size, void* d_ws, size_t ws_size,
                              hipStream_t stream) {
  (void)in_sizes; (void)n_in; (void)out_size; (void)ws_size;
  const float* x   = (const float*)d_in[0];
  const float* we1 = (const float*)d_in[1];
  const float* be1 = (const float*)d_in[2];
  const float* we2 = (const float*)d_in[3];
  const float* be2 = (const float*)d_in[4];
  const float* cb  = (const float*)d_in[5];
  const float* wd1 = (const float*)d_in[6];
  const float* bd1 = (const float*)d_in[7];
  const float* wd2 = (const float*)d_in[8];
  const float* bd2 = (const float*)d_in[9];
  float* out = (float*)d_out;
  char* ws = (char*)d_ws;

  hipLaunchKernelGGL(prep_frags, dim3(320), dim3(256), 0, stream, we2, wd1, cb, ws);
  hipLaunchKernelGGL(prep_cb, dim3(NCB), dim3(64), 0, stream, cb, ws);
  hipLaunchKernelGGL(prep_we, dim3(4), dim3(256), 0, stream, we1, be1, ws);
  hipLaunchKernelGGL(vq_main, dim3(NTOK / TILE_M), dim3(BLOCK), 0, stream,
                     x, be2, cb, bd1, wd2, bd2, ws, out);
}